// Round 3
// baseline (4556.961 us; speedup 1.0000x reference)
//
#include <hip/hip_runtime.h>

typedef __attribute__((ext_vector_type(8))) short short8;
typedef __attribute__((ext_vector_type(4))) float f32x4;
typedef unsigned short u16;

#define DEVI static __device__ __forceinline__

// BS=4 NQ=1024 D=256 NH=8 NP=4 L=6 DFF=1024 H=200 W=150 NV=30000 DH=32
// All d_in / d_out buffers are FP32 (reference dtype). Internals: bf16 MFMA,
// fp32 accumulate, fp32 residual stream + LN.
DEVI float b2f(u16 u){ unsigned int x = ((unsigned int)u) << 16; float f; __builtin_memcpy(&f, &x, 4); return f; }
DEVI u16 f2b(float f){ unsigned int u; __builtin_memcpy(&u, &f, 4); u += 0x7fffu + ((u >> 16) & 1u); return (u16)(u >> 16); }
DEVI short8 cvt8(const float* __restrict__ p){   // 8 fp32 -> bf16x8 fragment (RNE); p is 16B-aligned
  f32x4 a = *(const f32x4*)p;
  f32x4 b = *(const f32x4*)(p + 4);
  short8 r;
  r[0]=(short)f2b(a[0]); r[1]=(short)f2b(a[1]); r[2]=(short)f2b(a[2]); r[3]=(short)f2b(a[3]);
  r[4]=(short)f2b(b[0]); r[5]=(short)f2b(b[1]); r[6]=(short)f2b(b[2]); r[7]=(short)f2b(b[3]);
  return r;
}

// ---------------------------------------------------------------------------
// Generic GEMM: C[m][n] = sum_k A[m][k] * W[n][k] (+ bias[n]) (+ relu)
// A/W each either bf16 (ws) or fp32 (d_in), converted in-register.
// Block = 4 waves as 2x2 -> 128x128 tile; wave = 64x64 of 16x16x32 MFMA.
// ---------------------------------------------------------------------------
template<bool ABF, bool WBF, bool BIAS, bool RELU, bool OUTBF>
__global__ __launch_bounds__(256) void gemm_k(
    const void* __restrict__ Av, int lda, long sA2, long sA1,
    const void* __restrict__ Wv, int ldw, long sW2, long sW1,
    const float* __restrict__ bias,
    void* __restrict__ Cv, int ldo, long sC2, long sC1,
    int M, int N, int K, int zshift)
{
  const int z  = blockIdx.z;
  const int z2 = z >> zshift, z1 = z - (z2 << zshift);
  const long aoff = z2 * sA2 + z1 * sA1;
  const long woff = z2 * sW2 + z1 * sW1;
  const long coff = z2 * sC2 + z1 * sC1;
  const int wave = threadIdx.x >> 6, lane = threadIdx.x & 63;
  const int wm = wave >> 1, wn = wave & 1;
  const int bm = blockIdx.x * 128 + wm * 64;
  const int bn = blockIdx.y * 128 + wn * 64;
  const int lr = lane & 15, lq = lane >> 4;
  const int koff = lq * 8;
  f32x4 acc[4][4] = {};
  const short8 Z8 = {0,0,0,0,0,0,0,0};
  for (int k0 = 0; k0 < K; k0 += 32) {
    short8 af[4], bf[4];
#pragma unroll
    for (int i = 0; i < 4; i++) {
      int r = bm + i * 16 + lr;
      if (r < M) {
        long o = aoff + (long)r * lda + k0 + koff;
        af[i] = ABF ? *(const short8*)((const u16*)Av + o) : cvt8((const float*)Av + o);
      } else af[i] = Z8;
    }
#pragma unroll
    for (int j = 0; j < 4; j++) {
      int c = bn + j * 16 + lr;
      if (c < N) {
        long o = woff + (long)c * ldw + k0 + koff;
        bf[j] = WBF ? *(const short8*)((const u16*)Wv + o) : cvt8((const float*)Wv + o);
      } else bf[j] = Z8;
    }
#pragma unroll
    for (int i = 0; i < 4; i++)
#pragma unroll
      for (int j = 0; j < 4; j++)
        acc[i][j] = __builtin_amdgcn_mfma_f32_16x16x32_bf16(af[i], bf[j], acc[i][j], 0, 0, 0);
  }
#pragma unroll
  for (int j = 0; j < 4; j++) {
    int cc = bn + j * 16 + lr;
    if (cc >= N) continue;
    float bv = BIAS ? bias[cc] : 0.f;
#pragma unroll
    for (int i = 0; i < 4; i++) {
#pragma unroll
      for (int r = 0; r < 4; r++) {
        int rr = bm + i * 16 + lq * 4 + r;   // C/D: col=lane&15, row=quad*4+reg
        if (rr >= M) continue;
        float v = acc[i][j][r] + bv;
        if (RELU) v = fmaxf(v, 0.f);
        long idx = coff + (long)rr * ldo + cc;
        if (OUTBF) ((u16*)Cv)[idx] = f2b(v);
        else       ((float*)Cv)[idx] = v;
      }
    }
  }
}

// residual stream init: out_f32 = query (fp32 copy)
__global__ __launch_bounds__(256) void init_out_k(const float* __restrict__ q, float* __restrict__ out){
  long i = (long)blockIdx.x * 256 + threadIdx.x;
  out[i] = q[i];
}

// layer-start: qk_b = bf16(out + qpos), out_b = bf16(out)
__global__ __launch_bounds__(256) void prep_qk_k(const float* __restrict__ out_f, const float* __restrict__ qpos,
                                                 u16* __restrict__ qk_b, u16* __restrict__ out_b){
  long i = (long)blockIdx.x * 256 + threadIdx.x;
  float o = out_f[i];
  out_b[i] = f2b(o);
  qk_b[i]  = f2b(o + qpos[i]);
}

// V (4096 x 256, head-major cols, bf16) -> Vt[b][h][dh][q]
__global__ __launch_bounds__(256) void vt_k(const u16* __restrict__ V, u16* __restrict__ Vt){
  int tid = blockIdx.x * 256 + threadIdx.x;   // = ((b*8+h)*32+dh)*1024 + q
  int q = tid & 1023;
  int rest = tid >> 10;
  int dh = rest & 31, h = (rest >> 5) & 7, b = rest >> 8;
  Vt[tid] = V[(long)((b << 10) + q) * 256 + (h << 5) + dh];
}

// in-place softmax over rows of 1024 bf16 scores (scale applied in exponent)
__global__ __launch_bounds__(256) void softmax_k(u16* __restrict__ S, float scale){
  long row = blockIdx.x;
  u16* p = S + row * 1024;
  int t = threadIdx.x;
  float v[4]; float mx = -1e30f;
#pragma unroll
  for (int i = 0; i < 4; i++){ v[i] = b2f(p[t + i * 256]); mx = fmaxf(mx, v[i]); }
  __shared__ float red[256];
  red[t] = mx; __syncthreads();
  for (int s = 128; s > 0; s >>= 1){ if (t < s) red[t] = fmaxf(red[t], red[t + s]); __syncthreads(); }
  mx = red[0]; __syncthreads();
  float sum = 0.f;
#pragma unroll
  for (int i = 0; i < 4; i++){ v[i] = __expf((v[i] - mx) * scale); sum += v[i]; }
  red[t] = sum; __syncthreads();
  for (int s = 128; s > 0; s >>= 1){ if (t < s) red[t] += red[t + s]; __syncthreads(); }
  float inv = 1.f / red[0];
#pragma unroll
  for (int i = 0; i < 4; i++) p[t + i * 256] = f2b(v[i] * inv);
}

// out = LN(out + sub); optional bf16 mirror, +qpos bf16 mirror, fp32 hs write
template<bool QKPOS, bool HS, bool OUTBF>
__global__ __launch_bounds__(256) void add_ln_k(
    const float* __restrict__ sub,
    const float* __restrict__ w, const float* __restrict__ b,
    const float* __restrict__ qpos,
    float* __restrict__ out_f, u16* __restrict__ out_b,
    u16* __restrict__ qk_b, float* __restrict__ hs)
{
  int row = blockIdx.x, t = threadIdx.x;
  long idx = (long)row * 256 + t;
  float x = out_f[idx] + sub[idx];
  __shared__ float r1[256], r2[256];
  r1[t] = x; r2[t] = x * x; __syncthreads();
  for (int s = 128; s > 0; s >>= 1){ if (t < s){ r1[t] += r1[t + s]; r2[t] += r2[t + s]; } __syncthreads(); }
  float m = r1[0] * (1.f / 256.f);
  float var = r2[0] * (1.f / 256.f) - m * m;
  float y = (x - m) * rsqrtf(var + 1e-5f) * w[t] + b[t];
  out_f[idx] = y;
  if (OUTBF) out_b[idx] = f2b(y);
  if (QKPOS) qk_b[idx]  = f2b(y + qpos[idx]);
  if (HS)    hs[idx]    = y;
}

// deformable attention sampling for ONE batch b: thread = (q,h,dh);
// 32 dh lanes coalesce the 64B value reads.
__global__ __launch_bounds__(256) void msda_k(
    const float* __restrict__ refp,  // (4,1024,1,2) fp32 (full)
    const float* __restrict__ off,   // (4096,64) = (h,p,2) fp32 (full)
    const float* __restrict__ aw,    // (4096,32) = (h,p) fp32 (full)
    const u16* __restrict__ v,       // (30000, 256) bf16 -- THIS batch only
    u16* __restrict__ o,             // (4096,256) bf16 (full)
    int b)
{
  int tid = blockIdx.x * 256 + threadIdx.x;   // 0..262143
  int dh = tid & 31;
  int h  = (tid >> 5) & 7;
  int q  = tid >> 8;                          // 0..1023
  int bq = (b << 10) + q;
  float rx = refp[bq * 2 + 0];
  float ry = refp[bq * 2 + 1];
  const float* offp = off + (long)bq * 64 + h * 8;
  const float* awp  = aw  + (long)bq * 32 + h * 4;
  float a0 = awp[0], a1 = awp[1], a2 = awp[2], a3 = awp[3];
  float am = fmaxf(fmaxf(a0, a1), fmaxf(a2, a3));
  float e[4];
  e[0] = __expf(a0 - am); e[1] = __expf(a1 - am); e[2] = __expf(a2 - am); e[3] = __expf(a3 - am);
  float einv = 1.f / (e[0] + e[1] + e[2] + e[3]);
  const u16* vb = v + h * 32 + dh;
  float accv = 0.f;
#pragma unroll
  for (int pp = 0; pp < 4; pp++){
    // x = (rx + ox/W)*W - 0.5 = rx*W + ox - 0.5
    float x = rx * 150.f + offp[pp * 2 + 0] - 0.5f;
    float y = ry * 200.f + offp[pp * 2 + 1] - 0.5f;
    float x0 = floorf(x), y0 = floorf(y);
    float s = 0.f;
#pragma unroll
    for (int c = 0; c < 4; c++){
      int dx = c & 1, dy = c >> 1;
      float xi = x0 + dx, yi = y0 + dy;
      float wt = (1.f - fabsf(x - xi)) * (1.f - fabsf(y - yi));
      if (xi >= 0.f && xi < 150.f && yi >= 0.f && yi < 200.f && wt > 0.f) {
        int xc = (int)xi, yc = (int)yi;
        s += wt * b2f(vb[((long)yc * 150 + xc) * 256]);
      }
    }
    accv += e[pp] * einv * s;
  }
  o[(long)bq * 256 + h * 32 + dh] = f2b(accv);
}

__global__ __launch_bounds__(256) void refs_k(const float* __restrict__ r, float* __restrict__ dst){
  int i = blockIdx.x * 256 + threadIdx.x;   // 6*8192 = 49152
  dst[i] = r[i & 8191];
}

// ---------------------------------------------------------------------------
// modes: 0 = bf16A/fp32W/bias/bf16out   1 = bf16A/bf16W/nobias/bf16out (S,PV)
//        2 = bf16A/fp32W/bias/fp32out   3 = fp32A/fp32W/bias/bf16out (valproj)
//        4 = bf16A/fp32W/bias+relu/bf16out (ff1)
static inline void gemm(hipStream_t st, int mode,
    const void* A, int lda, long sA2, long sA1,
    const void* W, int ldw, long sW2, long sW1,
    const float* bias, void* C, int ldo, long sC2, long sC1,
    int M, int N, int K, int Z, int zshift)
{
  dim3 g((M + 127) / 128, (N + 127) / 128, Z), b(256, 1, 1);
  switch (mode) {
    case 0: gemm_k<true,  false, true,  false, true ><<<g, b, 0, st>>>(A, lda, sA2, sA1, W, ldw, sW2, sW1, bias, C, ldo, sC2, sC1, M, N, K, zshift); break;
    case 1: gemm_k<true,  true,  false, false, true ><<<g, b, 0, st>>>(A, lda, sA2, sA1, W, ldw, sW2, sW1, bias, C, ldo, sC2, sC1, M, N, K, zshift); break;
    case 2: gemm_k<true,  false, true,  false, false><<<g, b, 0, st>>>(A, lda, sA2, sA1, W, ldw, sW2, sW1, bias, C, ldo, sC2, sC1, M, N, K, zshift); break;
    case 3: gemm_k<false, false, true,  false, true ><<<g, b, 0, st>>>(A, lda, sA2, sA1, W, ldw, sW2, sW1, bias, C, ldo, sC2, sC1, M, N, K, zshift); break;
    case 4: gemm_k<true,  false, true,  true,  true ><<<g, b, 0, st>>>(A, lda, sA2, sA1, W, ldw, sW2, sW1, bias, C, ldo, sC2, sC1, M, N, K, zshift); break;
  }
}

extern "C" void kernel_launch(void* const* d_in, const int* in_sizes, int n_in,
                              void* d_out, int out_size, void* d_ws, size_t ws_size,
                              hipStream_t stream)
{
  (void)in_sizes; (void)n_in; (void)out_size; (void)ws_size;
  const float* query = (const float*)d_in[0];
  const float* qpos  = (const float*)d_in[1];
  const float* refp  = (const float*)d_in[2];
  const float* src   = (const float*)d_in[3];
  const float* sa_in_w  = (const float*)d_in[6];
  const float* sa_in_b  = (const float*)d_in[7];
  const float* sa_out_w = (const float*)d_in[8];
  const float* sa_out_b = (const float*)d_in[9];
  const float* off_w = (const float*)d_in[10];
  const float* off_b = (const float*)d_in[11];
  const float* aw_w  = (const float*)d_in[12];
  const float* aw_b  = (const float*)d_in[13];
  const float* val_w = (const float*)d_in[14];
  const float* val_b = (const float*)d_in[15];
  const float* cout_w = (const float*)d_in[16];
  const float* cout_b = (const float*)d_in[17];
  const float* n1w = (const float*)d_in[18]; const float* n1b = (const float*)d_in[19];
  const float* n2w = (const float*)d_in[20]; const float* n2b = (const float*)d_in[21];
  const float* n3w = (const float*)d_in[22]; const float* n3b = (const float*)d_in[23];
  const float* ff1w = (const float*)d_in[24]; const float* ff1b = (const float*)d_in[25];
  const float* ff2w = (const float*)d_in[26]; const float* ff2b = (const float*)d_in[27];

  // -------- workspace: 38 MB, phase-aliased --------
  char* base = (char*)d_ws;
  float* out_f = (float*)(base);                  // 4 MB  fp32 residual stream
  float* tmp_f = (float*)(base + (4u << 20));     // 4 MB  sublayer output fp32
  u16*   qk_b  = (u16*)  (base + (8u << 20));     // 2 MB  bf16(out + qpos)
  u16*   out_b = (u16*)  (base + (10u << 20));    // 2 MB  bf16(out)
  char*  U     =          base + (12u << 20);     // 26 MB phase-aliased union
  // SA phase layout in U:
  u16* qkbuf = (u16*)(U);                         // 4 MB  Q|K (4096 x 512)
  u16* vbuf  = (u16*)(U + (4u << 20));            // 2 MB  V (4096 x 256)
  u16* vt    = (u16*)(U + (6u << 20));            // 2 MB  V^T [b][h][dh][q]
  u16* obuf  = (u16*)(U + (8u << 20));            // 2 MB  attn out (4096 x 256)
  u16* sbuf  = (u16*)(U + (10u << 20));           // 16 MB S/P for ONE batch [8][1024][1024]
  // CA phase layout in U (aliases SA buffers -- all consumed by then):
  float* offb = (float*)(U);                      // 1 MB   (4096 x 64) fp32
  float* awbf = (float*)(U + (1u << 20));         // 0.5 MB (4096 x 32) fp32
  u16*   mo   = (u16*)  (U + (1536u << 10));      // 2 MB   msda out (4096 x 256)
  u16*   vsrc = (u16*)  (U + (3584u << 10));      // 15.4 MB value proj ONE batch (30000 x 256)
  // FFN phase layout in U:
  u16*   ffh  = (u16*)(U);                        // 8 MB   ffn hidden (4096 x 1024)

  float* hs = (float*)d_out;
  float* refs_out = hs + (long)6 * 4096 * 256;

  init_out_k<<<4096, 256, 0, stream>>>(query, out_f);
  for (int l = 0; l < 6; l++){
    const float* wsa = sa_in_w + (long)l * 768 * 256;
    const float* bsa = sa_in_b + l * 768;
    // ---- self attention ----
    prep_qk_k<<<4096, 256, 0, stream>>>(out_f, qpos, qk_b, out_b);
    gemm(stream, 0, qk_b, 256, 0, 0, wsa, 256, 0, 0, bsa,
         qkbuf, 512, 0, 0, 4096, 512, 256, 1, 0);                       // Q|K
    gemm(stream, 0, out_b, 256, 0, 0, wsa + 512 * 256, 256, 0, 0, bsa + 512,
         vbuf, 256, 0, 0, 4096, 256, 256, 1, 0);                        // V (from out, not qk)
    vt_k<<<4096, 256, 0, stream>>>(vbuf, vt);
    for (int b = 0; b < 4; b++){
      const u16* qb = qkbuf + (long)b * 524288;
      gemm(stream, 1, qb, 512, 0, 32, qb + 256, 512, 0, 32, nullptr,
           sbuf, 1024, 0, 1048576, 1024, 1024, 32, 8, 3);               // S = Q K^T (z=h)
      softmax_k<<<8192, 256, 0, stream>>>(sbuf, 0.17677669529663687f);  // 1/sqrt(32)
      gemm(stream, 1, sbuf, 1024, 0, 1048576, vt + (long)b * 262144, 1024, 0, 32768, nullptr,
           obuf + (long)b * 262144, 256, 0, 32, 1024, 32, 1024, 8, 3);  // O = P V
    }
    gemm(stream, 2, obuf, 256, 0, 0, sa_out_w + (long)l * 65536, 256, 0, 0, sa_out_b + l * 256,
         tmp_f, 256, 0, 0, 4096, 256, 256, 1, 0);
    add_ln_k<true, false, false><<<4096, 256, 0, stream>>>(
        tmp_f, n2w + l * 256, n2b + l * 256, qpos, out_f, nullptr, qk_b, nullptr);  // norm2
    // ---- deformable cross attention ----
    gemm(stream, 2, qk_b, 256, 0, 0, off_w + (long)l * 64 * 256, 256, 0, 0, off_b + l * 64,
         offb, 64, 0, 0, 4096, 64, 256, 1, 0);
    gemm(stream, 2, qk_b, 256, 0, 0, aw_w + (long)l * 32 * 256, 256, 0, 0, aw_b + l * 32,
         awbf, 32, 0, 0, 4096, 32, 256, 1, 0);
    for (int b = 0; b < 4; b++){
      gemm(stream, 3, src + (long)b * 7680000, 256, 0, 0, val_w + (long)l * 65536, 256, 0, 0,
           val_b + l * 256, vsrc, 256, 0, 0, 30000, 256, 256, 1, 0);    // value proj, one batch
      msda_k<<<1024, 256, 0, stream>>>(refp, offb, awbf, vsrc, mo, b);
    }
    gemm(stream, 2, mo, 256, 0, 0, cout_w + (long)l * 65536, 256, 0, 0, cout_b + l * 256,
         tmp_f, 256, 0, 0, 4096, 256, 256, 1, 0);
    add_ln_k<false, false, true><<<4096, 256, 0, stream>>>(
        tmp_f, n1w + l * 256, n1b + l * 256, nullptr, out_f, out_b, nullptr, nullptr);  // norm1
    // ---- ffn ----
    gemm(stream, 4, out_b, 256, 0, 0, ff1w + (long)l * 1024 * 256, 256, 0, 0, ff1b + l * 1024,
         ffh, 1024, 0, 0, 4096, 1024, 256, 1, 0);                       // relu
    gemm(stream, 2, ffh, 1024, 0, 0, ff2w + (long)l * 256 * 1024, 1024, 0, 0, ff2b + l * 256,
         tmp_f, 256, 0, 0, 4096, 256, 1024, 1, 0);
    add_ln_k<false, true, false><<<4096, 256, 0, stream>>>(
        tmp_f, n3w + l * 256, n3b + l * 256, nullptr, out_f, nullptr, nullptr,
        hs + (long)l * 1048576);                                        // norm3 + hs[l]
  }
  refs_k<<<192, 256, 0, stream>>>(refp, refs_out);
}

// Round 4
// 2331.568 us; speedup vs baseline: 1.9545x; 1.9545x over previous
//
#include <hip/hip_runtime.h>

typedef __attribute__((ext_vector_type(8))) short short8;
typedef __attribute__((ext_vector_type(4))) short short4v;
typedef __attribute__((ext_vector_type(4))) float f32x4;
typedef unsigned short u16;

#define DEVI static __device__ __forceinline__

// BS=4 NQ=1024 D=256 NH=8 NP=4 L=6 DFF=1024 H=200 W=150 NV=30000 DH=32
// All d_in / d_out buffers are FP32. Internals: bf16 MFMA, fp32 accumulate,
// fp32 residual stream + LN.
DEVI float b2f(u16 u){ unsigned int x = ((unsigned int)u) << 16; float f; __builtin_memcpy(&f, &x, 4); return f; }
DEVI u16 f2b(float f){ unsigned int u; __builtin_memcpy(&u, &f, 4); u += 0x7fffu + ((u >> 16) & 1u); return (u16)(u >> 16); }
DEVI short8 cvt8(const float* __restrict__ p){   // 8 fp32 -> bf16x8 (RNE), p 16B-aligned
  f32x4 a = *(const f32x4*)p;
  f32x4 b = *(const f32x4*)(p + 4);
  short8 r;
  r[0]=(short)f2b(a[0]); r[1]=(short)f2b(a[1]); r[2]=(short)f2b(a[2]); r[3]=(short)f2b(a[3]);
  r[4]=(short)f2b(b[0]); r[5]=(short)f2b(b[1]); r[6]=(short)f2b(b[2]); r[7]=(short)f2b(b[3]);
  return r;
}

// f32 -> bf16 bulk convert, 8 elems/thread
__global__ __launch_bounds__(256) void cvt_k(const float* __restrict__ s, u16* __restrict__ d, int n8){
  int i = blockIdx.x * 256 + threadIdx.x;
  if (i < n8) ((short8*)d)[i] = cvt8(s + (long)i * 8);
}

// ---------------------------------------------------------------------------
// 64x64-tile GEMM: C[m][n] = sum_k A[m][k]*W[n][k] (+bias)(+relu)
// 4 waves as 2x2, each wave 32x32 via 2x2 of 16x16x32 MFMA. Direct global
// fragment loads; low VGPR -> 8 waves/SIMD occupancy. z-batched.
// ---------------------------------------------------------------------------
template<bool ABF, bool WBF, bool BIAS, bool RELU, bool OUTBF>
__global__ __launch_bounds__(256) void gemm64_k(
    const void* __restrict__ Av, int lda, long sA2, long sA1,
    const void* __restrict__ Wv, int ldw, long sW2, long sW1,
    const float* __restrict__ bias,
    void* __restrict__ Cv, int ldo, long sC2, long sC1,
    int M, int N, int K, int zshift)
{
  const int z  = blockIdx.z;
  const int z2 = z >> zshift, z1 = z - (z2 << zshift);
  const long aoff = z2 * sA2 + z1 * sA1;
  const long woff = z2 * sW2 + z1 * sW1;
  const long coff = z2 * sC2 + z1 * sC1;
  const int wave = threadIdx.x >> 6, lane = threadIdx.x & 63;
  const int wm = wave >> 1, wn = wave & 1;
  const int bm = blockIdx.x * 64 + wm * 32;
  const int bn = blockIdx.y * 64 + wn * 32;
  const int lr = lane & 15, lq = lane >> 4;
  const int koff = lq * 8;
  f32x4 acc[2][2] = {};
  const short8 Z8 = {0,0,0,0,0,0,0,0};
  for (int k0 = 0; k0 < K; k0 += 32) {
    short8 af[2], bf[2];
#pragma unroll
    for (int i = 0; i < 2; i++) {
      int r = bm + i * 16 + lr;
      if (r < M) {
        long o = aoff + (long)r * lda + k0 + koff;
        af[i] = ABF ? *(const short8*)((const u16*)Av + o) : cvt8((const float*)Av + o);
      } else af[i] = Z8;
    }
#pragma unroll
    for (int j = 0; j < 2; j++) {
      int c = bn + j * 16 + lr;
      if (c < N) {
        long o = woff + (long)c * ldw + k0 + koff;
        bf[j] = WBF ? *(const short8*)((const u16*)Wv + o) : cvt8((const float*)Wv + o);
      } else bf[j] = Z8;
    }
#pragma unroll
    for (int i = 0; i < 2; i++)
#pragma unroll
      for (int j = 0; j < 2; j++)
        acc[i][j] = __builtin_amdgcn_mfma_f32_16x16x32_bf16(af[i], bf[j], acc[i][j], 0, 0, 0);
  }
#pragma unroll
  for (int j = 0; j < 2; j++) {
    int cc = bn + j * 16 + lr;
    if (cc >= N) continue;
    float bv = BIAS ? bias[cc] : 0.f;
#pragma unroll
    for (int i = 0; i < 2; i++) {
#pragma unroll
      for (int r = 0; r < 4; r++) {
        int rr = bm + i * 16 + lq * 4 + r;   // C/D: col=lane&15, row=quad*4+reg
        if (rr >= M) continue;
        float v = acc[i][j][r] + bv;
        if (RELU) v = fmaxf(v, 0.f);
        long idx = coff + (long)rr * ldo + cc;
        if (OUTBF) ((u16*)Cv)[idx] = f2b(v);
        else       ((float*)Cv)[idx] = v;
      }
    }
  }
}

// layer-0 init: out_f = query; out_b = bf16(query); qk_b = bf16(query+qpos)
__global__ __launch_bounds__(256) void init_prep_k(const float* __restrict__ q, const float* __restrict__ qpos,
                                                   float* __restrict__ out_f, u16* __restrict__ out_b,
                                                   u16* __restrict__ qk_b){
  long i = (long)blockIdx.x * 256 + threadIdx.x;
  float o = q[i];
  out_f[i] = o;
  out_b[i] = f2b(o);
  qk_b[i]  = f2b(o + qpos[i]);
}

// V (4096 x 256, head-major cols, bf16) -> Vt[b][h][dh][q]
__global__ __launch_bounds__(256) void vt_k(const u16* __restrict__ V, u16* __restrict__ Vt){
  int tid = blockIdx.x * 256 + threadIdx.x;   // = ((b*8+h)*32+dh)*1024 + q
  int q = tid & 1023;
  int rest = tid >> 10;
  int dh = rest & 31, h = (rest >> 5) & 7, b = rest >> 8;
  Vt[tid] = V[(long)((b << 10) + q) * 256 + (h << 5) + dh];
}

// in-place softmax over rows of 1024 bf16 scores (vectorized short4)
__global__ __launch_bounds__(256) void softmax_k(u16* __restrict__ S, float scale){
  long row = blockIdx.x;
  u16* p = S + row * 1024;
  int t = threadIdx.x;
  short4v sv = *(short4v*)(p + t * 4);
  float v[4]; float mx = -1e30f;
#pragma unroll
  for (int i = 0; i < 4; i++){ v[i] = b2f((u16)sv[i]); mx = fmaxf(mx, v[i]); }
  __shared__ float red[256];
  red[t] = mx; __syncthreads();
  for (int s = 128; s > 0; s >>= 1){ if (t < s) red[t] = fmaxf(red[t], red[t + s]); __syncthreads(); }
  mx = red[0]; __syncthreads();
  float sum = 0.f;
#pragma unroll
  for (int i = 0; i < 4; i++){ v[i] = __expf((v[i] - mx) * scale); sum += v[i]; }
  red[t] = sum; __syncthreads();
  for (int s = 128; s > 0; s >>= 1){ if (t < s) red[t] += red[t + s]; __syncthreads(); }
  float inv = 1.f / red[0];
#pragma unroll
  for (int i = 0; i < 4; i++) sv[i] = (short)f2b(v[i] * inv);
  *(short4v*)(p + t * 4) = sv;
}

// out = LN(out + sub); flags: emit qk_b(out+qpos), hs, out_b
template<bool QKPOS, bool HS, bool OUTB>
__global__ __launch_bounds__(256) void add_ln_k(
    const float* __restrict__ sub,
    const float* __restrict__ w, const float* __restrict__ b,
    const float* __restrict__ qpos,
    float* __restrict__ out_f, u16* __restrict__ out_b,
    u16* __restrict__ qk_b, float* __restrict__ hs)
{
  int row = blockIdx.x, t = threadIdx.x;
  long idx = (long)row * 256 + t;
  float x = out_f[idx] + sub[idx];
  __shared__ float r1[256], r2[256];
  r1[t] = x; r2[t] = x * x; __syncthreads();
  for (int s = 128; s > 0; s >>= 1){ if (t < s){ r1[t] += r1[t + s]; r2[t] += r2[t + s]; } __syncthreads(); }
  float m = r1[0] * (1.f / 256.f);
  float var = r2[0] * (1.f / 256.f) - m * m;
  float y = (x - m) * rsqrtf(var + 1e-5f) * w[t] + b[t];
  out_f[idx] = y;
  if (OUTB)  out_b[idx] = f2b(y);
  if (QKPOS) qk_b[idx]  = f2b(y + qpos[idx]);
  if (HS)    hs[idx]    = y;
}

// deformable sampling. grid covers (bbase..bbase+nb) batches; thread=(q,h,dh).
// v: base of value buffer; per-batch stride vstride elems (0 if pre-offset).
__global__ __launch_bounds__(256) void msda_k(
    const float* __restrict__ refp,  // (4,1024,1,2) fp32 (full)
    const float* __restrict__ off,   // (4096,64) fp32 (full)
    const float* __restrict__ aw,    // (4096,32) fp32 (full)
    const u16* __restrict__ v,       // bf16 values
    u16* __restrict__ o,             // (4096,256) bf16 (full)
    int bbase, long vstride)
{
  int tid = blockIdx.x * 256 + threadIdx.x;
  int dh = tid & 31;
  int h  = (tid >> 5) & 7;
  int qq = tid >> 8;
  int bq = (bbase << 10) + qq;
  int b  = bq >> 10;
  float rx = refp[bq * 2 + 0];
  float ry = refp[bq * 2 + 1];
  const float* offp = off + (long)bq * 64 + h * 8;
  const float* awp  = aw  + (long)bq * 32 + h * 4;
  float a0 = awp[0], a1 = awp[1], a2 = awp[2], a3 = awp[3];
  float am = fmaxf(fmaxf(a0, a1), fmaxf(a2, a3));
  float e[4];
  e[0] = __expf(a0 - am); e[1] = __expf(a1 - am); e[2] = __expf(a2 - am); e[3] = __expf(a3 - am);
  float einv = 1.f / (e[0] + e[1] + e[2] + e[3]);
  const u16* vb = v + b * vstride + h * 32 + dh;
  float accv = 0.f;
#pragma unroll
  for (int pp = 0; pp < 4; pp++){
    float x = rx * 150.f + offp[pp * 2 + 0] - 0.5f;
    float y = ry * 200.f + offp[pp * 2 + 1] - 0.5f;
    float x0 = floorf(x), y0 = floorf(y);
    float s = 0.f;
#pragma unroll
    for (int c = 0; c < 4; c++){
      int dx = c & 1, dy = c >> 1;
      float xi = x0 + dx, yi = y0 + dy;
      float wt = (1.f - fabsf(x - xi)) * (1.f - fabsf(y - yi));
      if (xi >= 0.f && xi < 150.f && yi >= 0.f && yi < 200.f && wt > 0.f) {
        int xc = (int)xi, yc = (int)yi;
        s += wt * b2f(vb[((long)yc * 150 + xc) * 256]);
      }
    }
    accv += e[pp] * einv * s;
  }
  o[(long)bq * 256 + h * 32 + dh] = f2b(accv);
}

__global__ __launch_bounds__(256) void refs_k(const float* __restrict__ r, float* __restrict__ dst){
  int i = blockIdx.x * 256 + threadIdx.x;   // 6*8192 = 49152
  dst[i] = r[i & 8191];
}

// ---------------------------------------------------------------------------
// modes: 0 A1W1 B1 O1 | 1 A1W1 B1 O0 | 2 A1W1 B0 O1 | 3 A1W1 B1 R O1
//        4 A1W0 B1 O1 | 5 A1W0 B1 O0 | 6 A1W0 B1 R O1 | 7 A0W0 B1 O1
static inline void g64(hipStream_t st, int mode,
    const void* A, int lda, long sA2, long sA1,
    const void* W, int ldw, long sW2, long sW1,
    const float* bias, void* C, int ldo, long sC2, long sC1,
    int M, int N, int K, int Z, int zs)
{
  dim3 g((M + 63) / 64, (N + 63) / 64, Z), b(256, 1, 1);
  switch (mode) {
    case 0: gemm64_k<true, true, true, false,true ><<<g,b,0,st>>>(A,lda,sA2,sA1,W,ldw,sW2,sW1,bias,C,ldo,sC2,sC1,M,N,K,zs); break;
    case 1: gemm64_k<true, true, true, false,false><<<g,b,0,st>>>(A,lda,sA2,sA1,W,ldw,sW2,sW1,bias,C,ldo,sC2,sC1,M,N,K,zs); break;
    case 2: gemm64_k<true, true, false,false,true ><<<g,b,0,st>>>(A,lda,sA2,sA1,W,ldw,sW2,sW1,bias,C,ldo,sC2,sC1,M,N,K,zs); break;
    case 3: gemm64_k<true, true, true, true, true ><<<g,b,0,st>>>(A,lda,sA2,sA1,W,ldw,sW2,sW1,bias,C,ldo,sC2,sC1,M,N,K,zs); break;
    case 4: gemm64_k<true, false,true, false,true ><<<g,b,0,st>>>(A,lda,sA2,sA1,W,ldw,sW2,sW1,bias,C,ldo,sC2,sC1,M,N,K,zs); break;
    case 5: gemm64_k<true, false,true, false,false><<<g,b,0,st>>>(A,lda,sA2,sA1,W,ldw,sW2,sW1,bias,C,ldo,sC2,sC1,M,N,K,zs); break;
    case 6: gemm64_k<true, false,true, true, true ><<<g,b,0,st>>>(A,lda,sA2,sA1,W,ldw,sW2,sW1,bias,C,ldo,sC2,sC1,M,N,K,zs); break;
    case 7: gemm64_k<false,false,true, false,true ><<<g,b,0,st>>>(A,lda,sA2,sA1,W,ldw,sW2,sW1,bias,C,ldo,sC2,sC1,M,N,K,zs); break;
  }
}

extern "C" void kernel_launch(void* const* d_in, const int* in_sizes, int n_in,
                              void* d_out, int out_size, void* d_ws, size_t ws_size,
                              hipStream_t stream)
{
  (void)in_sizes; (void)n_in; (void)out_size;
  const float* query = (const float*)d_in[0];
  const float* qpos  = (const float*)d_in[1];
  const float* refp  = (const float*)d_in[2];
  const float* src   = (const float*)d_in[3];
  const float* sa_in_w  = (const float*)d_in[6];
  const float* sa_in_b  = (const float*)d_in[7];
  const float* sa_out_w = (const float*)d_in[8];
  const float* sa_out_b = (const float*)d_in[9];
  const float* off_w = (const float*)d_in[10];
  const float* off_b = (const float*)d_in[11];
  const float* aw_w  = (const float*)d_in[12];
  const float* aw_b  = (const float*)d_in[13];
  const float* val_w = (const float*)d_in[14];
  const float* val_b = (const float*)d_in[15];
  const float* cout_w = (const float*)d_in[16];
  const float* cout_b = (const float*)d_in[17];
  const float* n1w = (const float*)d_in[18]; const float* n1b = (const float*)d_in[19];
  const float* n2w = (const float*)d_in[20]; const float* n2b = (const float*)d_in[21];
  const float* n3w = (const float*)d_in[22]; const float* n3b = (const float*)d_in[23];
  const float* ff1w = (const float*)d_in[24]; const float* ff1b = (const float*)d_in[25];
  const float* ff2w = (const float*)d_in[26]; const float* ff2b = (const float*)d_in[27];

  float* hs = (float*)d_out;
  float* refs_out = hs + (long)6 * 4096 * 256;

  // ---- common small buffers ----
  char* base = (char*)d_ws;
  float* out_f = (float*)(base);                  // 4 MB
  float* tmp_f = (float*)(base + (4u << 20));     // 4 MB
  u16*   qk_b  = (u16*)  (base + (8u << 20));     // 2 MB
  u16*   out_b = (u16*)  (base + (10u << 20));    // 2 MB
  char*  rest  =          base + (12u << 20);

  // PLAN A footprint: 12M + weights(11.3M) + src_b(61.4M) + union(77.6M) ~ 163M
  const size_t NEED_A = 170u << 20;
  const bool planA = (ws_size >= NEED_A);

  init_prep_k<<<4096, 256, 0, stream>>>(query, qpos, out_f, out_b, qk_b);

  if (planA) {
    // weights (bf16, persistent)
    u16* wsa_b  = (u16*)(rest);                       // 6*768*256
    u16* wsao_b = wsa_b  + 1179648;                   // 6*256*256
    u16* woff_b = wsao_b + 393216;                    // 6*64*256
    u16* waw_b  = woff_b + 98304;                     // 6*32*256
    u16* wval_b = waw_b  + 49152;                     // 6*256*256
    u16* wcao_b = wval_b + 393216;                    // 6*256*256
    u16* wff1_b = wcao_b + 393216;                    // 6*1024*256
    u16* wff2_b = wff1_b + 1572864;                   // 6*256*1024
    u16* src_b  = wff2_b + 1572864;                   // 4*30000*256
    char* U = (char*)(src_b + 30720000);
    // SA phase:
    u16* qkbuf = (u16*)(U);                           // 4 MB (4096x512)
    u16* vbuf  = (u16*)(U + (4u << 20));              // 2 MB
    u16* vt    = (u16*)(U + (6u << 20));              // 2 MB
    u16* obuf  = (u16*)(U + (8u << 20));              // 2 MB
    u16* sbuf  = (u16*)(U + (10u << 20));             // 64 MB [b][h][1024][1024]
    // CA phase (aliases SA, all consumed):
    float* offb = (float*)(U);                        // 1 MB
    float* awbf = (float*)(U + (1u << 20));           // 0.5 MB
    u16*   mo   = (u16*)  (U + (1536u << 10));        // 2 MB
    u16*   vsrc = (u16*)  (U + (3584u << 10));        // 58.6 MB (120000x256)
    // FFN phase:
    u16*   ffh  = (u16*)(U);                          // 8 MB

    // one-time converts (per call)
    auto cv = [&](const float* s, u16* d, int n){ cvt_k<<<(n/8 + 255)/256, 256, 0, stream>>>(s, d, n/8); };
    cv(sa_in_w,  wsa_b,  1179648*8/8); cv(sa_out_w, wsao_b, 393216);
    cv(off_w,    woff_b, 98304);       cv(aw_w,     waw_b,  49152);
    cv(val_w,    wval_b, 393216);      cv(cout_w,   wcao_b, 393216);
    cv(ff1w,     wff1_b, 1572864);     cv(ff2w,     wff2_b, 1572864);
    cv(src,      src_b,  30720000);

    for (int l = 0; l < 6; l++){
      const u16* wsa = wsa_b + (long)l * 768 * 256;
      const float* bsa = sa_in_b + l * 768;
      // ---- self attention ----
      g64(stream, 0, qk_b, 256,0,0, wsa, 256,0,0, bsa, qkbuf, 512,0,0, 4096,512,256, 1,0);
      g64(stream, 0, out_b,256,0,0, wsa + 512*256, 256,0,0, bsa + 512, vbuf, 256,0,0, 4096,256,256, 1,0);
      vt_k<<<4096, 256, 0, stream>>>(vbuf, vt);
      g64(stream, 2, qkbuf, 512, 524288, 32, qkbuf + 256, 512, 524288, 32, nullptr,
          sbuf, 1024, 8388608, 1048576, 1024, 1024, 32, 32, 3);          // S = Q K^T
      softmax_k<<<32768, 256, 0, stream>>>(sbuf, 0.17677669529663687f);
      g64(stream, 2, sbuf, 1024, 8388608, 1048576, vt, 1024, 262144, 32768, nullptr,
          obuf, 256, 262144, 32, 1024, 32, 1024, 32, 3);                 // O = P V
      g64(stream, 1, obuf, 256,0,0, wsao_b + (long)l*65536, 256,0,0, sa_out_b + l*256,
          tmp_f, 256,0,0, 4096,256,256, 1,0);
      add_ln_k<true,false,false><<<4096,256,0,stream>>>(tmp_f, n2w+l*256, n2b+l*256, qpos,
          out_f, nullptr, qk_b, nullptr);
      // ---- deformable cross attention ----
      g64(stream, 1, qk_b, 256,0,0, woff_b + (long)l*16384, 256,0,0, off_b + l*64,
          offb, 64,0,0, 4096,64,256, 1,0);
      g64(stream, 1, qk_b, 256,0,0, waw_b + (long)l*8192, 256,0,0, aw_b + l*32,
          awbf, 32,0,0, 4096,32,256, 1,0);
      g64(stream, 0, src_b, 256,0,0, wval_b + (long)l*65536, 256,0,0, val_b + l*256,
          vsrc, 256,0,0, 120000,256,256, 1,0);                           // value proj, all batches
      msda_k<<<4096, 256, 0, stream>>>(refp, offb, awbf, vsrc, mo, 0, 7680000);
      g64(stream, 1, mo, 256,0,0, wcao_b + (long)l*65536, 256,0,0, cout_b + l*256,
          tmp_f, 256,0,0, 4096,256,256, 1,0);
      add_ln_k<false,false,true><<<4096,256,0,stream>>>(tmp_f, n1w+l*256, n1b+l*256, nullptr,
          out_f, out_b, nullptr, nullptr);
      // ---- ffn ----
      g64(stream, 3, out_b, 256,0,0, wff1_b + (long)l*262144, 256,0,0, ff1b + l*1024,
          ffh, 1024,0,0, 4096,1024,256, 1,0);
      g64(stream, 1, ffh, 1024,0,0, wff2_b + (long)l*262144, 1024,0,0, ff2b + l*256,
          tmp_f, 256,0,0, 4096,256,1024, 1,0);
      add_ln_k<true,true,true><<<4096,256,0,stream>>>(tmp_f, n3w+l*256, n3b+l*256, qpos,
          out_f, out_b, qk_b, hs + (long)l*1048576);
    }
  } else {
    // -------- PLAN B: round-3-proven chunked layout, 64-tile GEMM ----------
    char* U = rest;                                   // 26 MB union
    u16* qkbuf = (u16*)(U);
    u16* vbuf  = (u16*)(U + (4u << 20));
    u16* vt    = (u16*)(U + (6u << 20));
    u16* obuf  = (u16*)(U + (8u << 20));
    u16* sbuf  = (u16*)(U + (10u << 20));             // 16 MB, one batch
    float* offb = (float*)(U);
    float* awbf = (float*)(U + (1u << 20));
    u16*   mo   = (u16*)  (U + (1536u << 10));
    u16*   vsrc = (u16*)  (U + (3584u << 10));        // 15.4 MB, one batch
    u16*   ffh  = (u16*)(U);

    for (int l = 0; l < 6; l++){
      const float* wsa = sa_in_w + (long)l * 768 * 256;
      const float* bsa = sa_in_b + l * 768;
      g64(stream, 4, qk_b, 256,0,0, wsa, 256,0,0, bsa, qkbuf, 512,0,0, 4096,512,256, 1,0);
      g64(stream, 4, out_b,256,0,0, wsa + 512*256, 256,0,0, bsa + 512, vbuf, 256,0,0, 4096,256,256, 1,0);
      vt_k<<<4096, 256, 0, stream>>>(vbuf, vt);
      for (int b = 0; b < 4; b++){
        const u16* qb = qkbuf + (long)b * 524288;
        g64(stream, 2, qb, 512, 0, 32, qb + 256, 512, 0, 32, nullptr,
            sbuf, 1024, 0, 1048576, 1024, 1024, 32, 8, 3);
        softmax_k<<<8192, 256, 0, stream>>>(sbuf, 0.17677669529663687f);
        g64(stream, 2, sbuf, 1024, 0, 1048576, vt + (long)b*262144, 1024, 0, 32768, nullptr,
            obuf + (long)b*262144, 256, 0, 32, 1024, 32, 1024, 8, 3);
      }
      g64(stream, 5, obuf, 256,0,0, sa_out_w + (long)l*65536, 256,0,0, sa_out_b + l*256,
          tmp_f, 256,0,0, 4096,256,256, 1,0);
      add_ln_k<true,false,false><<<4096,256,0,stream>>>(tmp_f, n2w+l*256, n2b+l*256, qpos,
          out_f, nullptr, qk_b, nullptr);
      g64(stream, 5, qk_b, 256,0,0, off_w + (long)l*16384, 256,0,0, off_b + l*64,
          offb, 64,0,0, 4096,64,256, 1,0);
      g64(stream, 5, qk_b, 256,0,0, aw_w + (long)l*8192, 256,0,0, aw_b + l*32,
          awbf, 32,0,0, 4096,32,256, 1,0);
      for (int b = 0; b < 4; b++){
        g64(stream, 7, src + (long)b*7680000, 256,0,0, val_w + (long)l*65536, 256,0,0,
            val_b + l*256, vsrc, 256,0,0, 30000,256,256, 1,0);
        msda_k<<<1024, 256, 0, stream>>>(refp, offb, awbf, vsrc, mo, b, 0);
      }
      g64(stream, 5, mo, 256,0,0, cout_w + (long)l*65536, 256,0,0, cout_b + l*256,
          tmp_f, 256,0,0, 4096,256,256, 1,0);
      add_ln_k<false,false,true><<<4096,256,0,stream>>>(tmp_f, n1w+l*256, n1b+l*256, nullptr,
          out_f, out_b, nullptr, nullptr);
      g64(stream, 6, out_b, 256,0,0, ff1w + (long)l*262144, 256,0,0, ff1b + l*1024,
          ffh, 1024,0,0, 4096,1024,256, 1,0);
      g64(stream, 5, ffh, 1024,0,0, ff2w + (long)l*262144, 1024,0,0, ff2b + l*256,
          tmp_f, 256,0,0, 4096,256,1024, 1,0);
      add_ln_k<true,true,true><<<4096,256,0,stream>>>(tmp_f, n3w+l*256, n3b+l*256, qpos,
          out_f, out_b, qk_b, hs + (long)l*1048576);
    }
  }
  refs_k<<<192, 256, 0, stream>>>(refp, refs_out);
}

// Round 5
// 2194.431 us; speedup vs baseline: 2.0766x; 1.0625x over previous
//
#include <hip/hip_runtime.h>

typedef __attribute__((ext_vector_type(8))) short short8;
typedef __attribute__((ext_vector_type(4))) short short4v;
typedef __attribute__((ext_vector_type(4))) float f32x4;
typedef unsigned short u16;

#define DEVI static __device__ __forceinline__

// BS=4 NQ=1024 D=256 NH=8 NP=4 L=6 DFF=1024 H=200 W=150 NV=30000 DH=32
// d_in/d_out are FP32. Internals: bf16 MFMA, fp32 accum, fp32 residual+LN.
DEVI float b2f(u16 u){ unsigned int x = ((unsigned int)u) << 16; float f; __builtin_memcpy(&f, &x, 4); return f; }
DEVI u16 f2b(float f){ unsigned int u; __builtin_memcpy(&u, &f, 4); u += 0x7fffu + ((u >> 16) & 1u); return (u16)(u >> 16); }
DEVI short8 cvt8(const float* __restrict__ p){
  f32x4 a = *(const f32x4*)p;
  f32x4 b = *(const f32x4*)(p + 4);
  short8 r;
  r[0]=(short)f2b(a[0]); r[1]=(short)f2b(a[1]); r[2]=(short)f2b(a[2]); r[3]=(short)f2b(a[3]);
  r[4]=(short)f2b(b[0]); r[5]=(short)f2b(b[1]); r[6]=(short)f2b(b[2]); r[7]=(short)f2b(b[3]);
  return r;
}

__global__ __launch_bounds__(256) void cvt_k(const float* __restrict__ s, u16* __restrict__ d, int n8){
  int i = blockIdx.x * 256 + threadIdx.x;
  if (i < n8) ((short8*)d)[i] = cvt8(s + (long)i * 8);
}

// pack off_w|aw_w -> wofaw (bf16, [l][96][256]) and off_b|aw_b -> obc (fp32, [l][96])
__global__ __launch_bounds__(256) void offaw_pack_k(
    const float* __restrict__ off_w, const float* __restrict__ aw_w,
    const float* __restrict__ off_b, const float* __restrict__ aw_b,
    u16* __restrict__ wofaw, float* __restrict__ obc)
{
  int tid = blockIdx.x * 256 + threadIdx.x;
  if (tid < 98304) {                        // off W: 6*64*256
    int l = tid / 16384, rem = tid - l * 16384;
    wofaw[l * 24576 + rem] = f2b(off_w[tid]);
  } else if (tid < 147456) {                // aw W: 6*32*256
    int t2 = tid - 98304;
    int l = t2 / 8192, rem = t2 - l * 8192;
    wofaw[l * 24576 + 16384 + rem] = f2b(aw_w[t2]);
  } else if (tid < 147840) {                // off bias: 6*64
    int t3 = tid - 147456;
    obc[(t3 / 64) * 96 + (t3 % 64)] = off_b[t3];
  } else if (tid < 148032) {                // aw bias: 6*32
    int t4 = tid - 147840;
    obc[(t4 / 32) * 96 + 64 + (t4 % 32)] = aw_b[t4];
  }
}

// ---------------------------------------------------------------------------
// gemm_w_k: 64(M) x 256(N) block; 4 waves side-by-side (wave w = cols w*64..).
// A[64][256] chunk staged in LDS via global_load_lds (16B); W streamed (L2).
// C = A W^T + bias. Optional: RELU, bf16 out, fused V^T store, fused
// residual+LayerNorm epilogue (writes out_f/out_b/qk_b/hs directly).
// Requirements: M%64==0, N%256==0 covered by grid.y, K%256==0, lda>=K contig.
// ---------------------------------------------------------------------------
template<bool RELU, bool OUTBF, bool VT, bool LN>
__global__ __launch_bounds__(256) void gemm_w_k(
    const u16* __restrict__ A, int lda,
    const u16* __restrict__ W,              // ldw == K
    const float* __restrict__ bias,
    void* __restrict__ Cv, int ldo,
    int M, int N, int K,
    u16* __restrict__ vt,                   // VT only
    const float* __restrict__ res,          // LN: residual stream in
    const float* __restrict__ lnw, const float* __restrict__ lnb,
    const float* __restrict__ qpos,        // LN (nullable)
    float* __restrict__ out_f, u16* __restrict__ out_b16,
    u16* __restrict__ qk_b16, float* __restrict__ hsp)
{
  __shared__ u16 As[32][64][8];            // [kgrp][row][8 elems] = 32 KB
  __shared__ float r1s[4][64], r2s[4][64], mArr[64], iArr[64];
  const int wave = threadIdx.x >> 6, lane = threadIdx.x & 63;
  const int bm = blockIdx.x * 64;
  const int bn = blockIdx.y * 256 + wave * 64;
  const int lr = lane & 15, lq = lane >> 4;
  f32x4 acc[4][4] = {};
  const int nchunks = K >> 8;
  for (int ch = 0; ch < nchunks; ch++) {
    const u16* ga = A + (long)(bm + lane) * lda + ch * 256;
#pragma unroll
    for (int g = 0; g < 8; g++) {
      int kgrp = wave * 8 + g;
      __builtin_amdgcn_global_load_lds(
          (const __attribute__((address_space(1))) void*)(ga + kgrp * 8),
          (__attribute__((address_space(3))) void*)&As[kgrp][0][0], 16, 0, 0);
    }
    __syncthreads();
#pragma unroll
    for (int s = 0; s < 8; s++) {
      short8 af[4], bf[4];
#pragma unroll
      for (int i = 0; i < 4; i++)
        af[i] = *(const short8*)&As[s * 4 + lq][i * 16 + lr][0];
#pragma unroll
      for (int j = 0; j < 4; j++) {
        int cc = bn + j * 16 + lr;
        bf[j] = *(const short8*)(W + (long)cc * K + ch * 256 + s * 32 + lq * 8);
      }
#pragma unroll
      for (int i = 0; i < 4; i++)
#pragma unroll
        for (int j = 0; j < 4; j++)
          acc[i][j] = __builtin_amdgcn_mfma_f32_16x16x32_bf16(af[i], bf[j], acc[i][j], 0, 0, 0);
    }
    __syncthreads();
  }

  float bv[4];
#pragma unroll
  for (int j = 0; j < 4; j++) bv[j] = bias[bn + j * 16 + lr];

  if (!LN) {
#pragma unroll
    for (int j = 0; j < 4; j++) {
      int cc = bn + j * 16 + lr;
#pragma unroll
      for (int i = 0; i < 4; i++) {
#pragma unroll
        for (int r = 0; r < 4; r++) {
          int rr = bm + i * 16 + lq * 4 + r;
          float v = acc[i][j][r] + bv[j];
          if (RELU) v = fmaxf(v, 0.f);
          long idx = (long)rr * ldo + cc;
          if (OUTBF) ((u16*)Cv)[idx] = f2b(v);
          else       ((float*)Cv)[idx] = v;
          if (VT) {
            int b_ = rr >> 10, q_ = rr & 1023, h_ = cc >> 5, dh_ = cc & 31;
            vt[(long)((((b_ << 3) + h_) << 5) + dh_) * 1024 + q_] = f2b(v);
          }
        }
      }
    }
  } else {
    // fused residual + LayerNorm over D=256 (ldo/stride fixed at 256)
    float s1[4][4] = {}, s2[4][4] = {};
#pragma unroll
    for (int i = 0; i < 4; i++) {
#pragma unroll
      for (int r = 0; r < 4; r++) {
        int rowg = bm + i * 16 + lq * 4 + r;
#pragma unroll
        for (int j = 0; j < 4; j++) {
          int cc = bn + j * 16 + lr;
          float x = acc[i][j][r] + bv[j] + res[(long)rowg * 256 + cc];
          s1[i][r] += x; s2[i][r] += x * x;
        }
      }
    }
#pragma unroll
    for (int i = 0; i < 4; i++)
#pragma unroll
      for (int r = 0; r < 4; r++) {
#pragma unroll
        for (int m = 1; m <= 8; m <<= 1) {
          s1[i][r] += __shfl_xor(s1[i][r], m);
          s2[i][r] += __shfl_xor(s2[i][r], m);
        }
      }
    if (lr == 0) {
#pragma unroll
      for (int i = 0; i < 4; i++)
#pragma unroll
        for (int r = 0; r < 4; r++) {
          int rl = i * 16 + lq * 4 + r;
          r1s[wave][rl] = s1[i][r];
          r2s[wave][rl] = s2[i][r];
        }
    }
    __syncthreads();
    if (threadIdx.x < 64) {
      int t = threadIdx.x;
      float a = r1s[0][t] + r1s[1][t] + r1s[2][t] + r1s[3][t];
      float b = r2s[0][t] + r2s[1][t] + r2s[2][t] + r2s[3][t];
      float m = a * (1.f / 256.f);
      float var = b * (1.f / 256.f) - m * m;
      mArr[t] = m;
      iArr[t] = rsqrtf(var + 1e-5f);
    }
    __syncthreads();
#pragma unroll
    for (int i = 0; i < 4; i++) {
#pragma unroll
      for (int r = 0; r < 4; r++) {
        int rl = i * 16 + lq * 4 + r;
        int rowg = bm + rl;
        float m = mArr[rl], inv = iArr[rl];
#pragma unroll
        for (int j = 0; j < 4; j++) {
          int cc = bn + j * 16 + lr;
          long idx = (long)rowg * 256 + cc;
          float x = acc[i][j][r] + bv[j] + res[idx];
          float y = (x - m) * inv * lnw[cc] + lnb[cc];
          out_f[idx] = y;
          if (out_b16) out_b16[idx] = f2b(y);
          if (qk_b16)  qk_b16[idx]  = f2b(y + qpos[idx]);
          if (hsp)     hsp[idx]     = y;
        }
      }
    }
  }
}

// ---------------------------------------------------------------------------
// gemm64_k (round-4 proven): 64x64 block, direct loads. Used for S, PV, offaw
// and the Plan-B fallback.
// ---------------------------------------------------------------------------
template<bool ABF, bool WBF, bool BIAS, bool RELU, bool OUTBF>
__global__ __launch_bounds__(256) void gemm64_k(
    const void* __restrict__ Av, int lda, long sA2, long sA1,
    const void* __restrict__ Wv, int ldw, long sW2, long sW1,
    const float* __restrict__ bias,
    void* __restrict__ Cv, int ldo, long sC2, long sC1,
    int M, int N, int K, int zshift)
{
  const int z  = blockIdx.z;
  const int z2 = z >> zshift, z1 = z - (z2 << zshift);
  const long aoff = z2 * sA2 + z1 * sA1;
  const long woff = z2 * sW2 + z1 * sW1;
  const long coff = z2 * sC2 + z1 * sC1;
  const int wave = threadIdx.x >> 6, lane = threadIdx.x & 63;
  const int wm = wave >> 1, wn = wave & 1;
  const int bm = blockIdx.x * 64 + wm * 32;
  const int bn = blockIdx.y * 64 + wn * 32;
  const int lr = lane & 15, lq = lane >> 4;
  const int koff = lq * 8;
  f32x4 acc[2][2] = {};
  const short8 Z8 = {0,0,0,0,0,0,0,0};
  for (int k0 = 0; k0 < K; k0 += 32) {
    short8 af[2], bf[2];
#pragma unroll
    for (int i = 0; i < 2; i++) {
      int r = bm + i * 16 + lr;
      if (r < M) {
        long o = aoff + (long)r * lda + k0 + koff;
        af[i] = ABF ? *(const short8*)((const u16*)Av + o) : cvt8((const float*)Av + o);
      } else af[i] = Z8;
    }
#pragma unroll
    for (int j = 0; j < 2; j++) {
      int c = bn + j * 16 + lr;
      if (c < N) {
        long o = woff + (long)c * ldw + k0 + koff;
        bf[j] = WBF ? *(const short8*)((const u16*)Wv + o) : cvt8((const float*)Wv + o);
      } else bf[j] = Z8;
    }
#pragma unroll
    for (int i = 0; i < 2; i++)
#pragma unroll
      for (int j = 0; j < 2; j++)
        acc[i][j] = __builtin_amdgcn_mfma_f32_16x16x32_bf16(af[i], bf[j], acc[i][j], 0, 0, 0);
  }
#pragma unroll
  for (int j = 0; j < 2; j++) {
    int cc = bn + j * 16 + lr;
    if (cc >= N) continue;
    float bv = BIAS ? bias[cc] : 0.f;
#pragma unroll
    for (int i = 0; i < 2; i++) {
#pragma unroll
      for (int r = 0; r < 4; r++) {
        int rr = bm + i * 16 + lq * 4 + r;
        if (rr >= M) continue;
        float v = acc[i][j][r] + bv;
        if (RELU) v = fmaxf(v, 0.f);
        long idx = coff + (long)rr * ldo + cc;
        if (OUTBF) ((u16*)Cv)[idx] = f2b(v);
        else       ((float*)Cv)[idx] = v;
      }
    }
  }
}

__global__ __launch_bounds__(256) void init_prep_k(const float* __restrict__ q, const float* __restrict__ qpos,
                                                   float* __restrict__ out_f, u16* __restrict__ out_b,
                                                   u16* __restrict__ qk_b){
  long i = (long)blockIdx.x * 256 + threadIdx.x;
  float o = q[i];
  out_f[i] = o;
  out_b[i] = f2b(o);
  qk_b[i]  = f2b(o + qpos[i]);
}

// V (4096x256 bf16) -> Vt[b][h][dh][q]  (Plan B only)
__global__ __launch_bounds__(256) void vt_k(const u16* __restrict__ V, u16* __restrict__ Vt){
  int tid = blockIdx.x * 256 + threadIdx.x;
  int q = tid & 1023;
  int rest = tid >> 10;
  int dh = rest & 31, h = (rest >> 5) & 7, b = rest >> 8;
  Vt[tid] = V[(long)((b << 10) + q) * 256 + (h << 5) + dh];
}

__global__ __launch_bounds__(256) void softmax_k(u16* __restrict__ S, float scale){
  long row = blockIdx.x;
  u16* p = S + row * 1024;
  int t = threadIdx.x;
  short4v sv = *(short4v*)(p + t * 4);
  float v[4]; float mx = -1e30f;
#pragma unroll
  for (int i = 0; i < 4; i++){ v[i] = b2f((u16)sv[i]); mx = fmaxf(mx, v[i]); }
  __shared__ float red[256];
  red[t] = mx; __syncthreads();
  for (int s = 128; s > 0; s >>= 1){ if (t < s) red[t] = fmaxf(red[t], red[t + s]); __syncthreads(); }
  mx = red[0]; __syncthreads();
  float sum = 0.f;
#pragma unroll
  for (int i = 0; i < 4; i++){ v[i] = __expf((v[i] - mx) * scale); sum += v[i]; }
  red[t] = sum; __syncthreads();
  for (int s = 128; s > 0; s >>= 1){ if (t < s) red[t] += red[t + s]; __syncthreads(); }
  float inv = 1.f / red[0];
#pragma unroll
  for (int i = 0; i < 4; i++) sv[i] = (short)f2b(v[i] * inv);
  *(short4v*)(p + t * 4) = sv;
}

template<bool QKPOS, bool HS, bool OUTB>
__global__ __launch_bounds__(256) void add_ln_k(
    const float* __restrict__ sub,
    const float* __restrict__ w, const float* __restrict__ b,
    const float* __restrict__ qpos,
    float* __restrict__ out_f, u16* __restrict__ out_b,
    u16* __restrict__ qk_b, float* __restrict__ hs)
{
  int row = blockIdx.x, t = threadIdx.x;
  long idx = (long)row * 256 + t;
  float x = out_f[idx] + sub[idx];
  __shared__ float r1[256], r2[256];
  r1[t] = x; r2[t] = x * x; __syncthreads();
  for (int s = 128; s > 0; s >>= 1){ if (t < s){ r1[t] += r1[t + s]; r2[t] += r2[t + s]; } __syncthreads(); }
  float m = r1[0] * (1.f / 256.f);
  float var = r2[0] * (1.f / 256.f) - m * m;
  float y = (x - m) * rsqrtf(var + 1e-5f) * w[t] + b[t];
  out_f[idx] = y;
  if (OUTB)  out_b[idx] = f2b(y);
  if (QKPOS) qk_b[idx]  = f2b(y + qpos[idx]);
  if (HS)    hs[idx]    = y;
}

// deformable sampling; thread=(q,h,dh). off/aw may share a combined buffer.
__global__ __launch_bounds__(256) void msda_k(
    const float* __restrict__ refp,
    const float* __restrict__ off, int ldoff,
    const float* __restrict__ aw, int ldaw,
    const u16* __restrict__ v,
    u16* __restrict__ o,
    int bbase, long vstride)
{
  int tid = blockIdx.x * 256 + threadIdx.x;
  int dh = tid & 31;
  int h  = (tid >> 5) & 7;
  int qq = tid >> 8;
  int bq = (bbase << 10) + qq;
  int b  = bq >> 10;
  float rx = refp[bq * 2 + 0];
  float ry = refp[bq * 2 + 1];
  const float* offp = off + (long)bq * ldoff + h * 8;
  const float* awp  = aw  + (long)bq * ldaw + h * 4;
  float a0 = awp[0], a1 = awp[1], a2 = awp[2], a3 = awp[3];
  float am = fmaxf(fmaxf(a0, a1), fmaxf(a2, a3));
  float e[4];
  e[0] = __expf(a0 - am); e[1] = __expf(a1 - am); e[2] = __expf(a2 - am); e[3] = __expf(a3 - am);
  float einv = 1.f / (e[0] + e[1] + e[2] + e[3]);
  const u16* vb = v + b * vstride + h * 32 + dh;
  float accv = 0.f;
#pragma unroll
  for (int pp = 0; pp < 4; pp++){
    float x = rx * 150.f + offp[pp * 2 + 0] - 0.5f;
    float y = ry * 200.f + offp[pp * 2 + 1] - 0.5f;
    float x0 = floorf(x), y0 = floorf(y);
    float s = 0.f;
#pragma unroll
    for (int c = 0; c < 4; c++){
      int dx = c & 1, dy = c >> 1;
      float xi = x0 + dx, yi = y0 + dy;
      float wt = (1.f - fabsf(x - xi)) * (1.f - fabsf(y - yi));
      if (xi >= 0.f && xi < 150.f && yi >= 0.f && yi < 200.f && wt > 0.f) {
        int xc = (int)xi, yc = (int)yi;
        s += wt * b2f(vb[((long)yc * 150 + xc) * 256]);
      }
    }
    accv += e[pp] * einv * s;
  }
  o[(long)bq * 256 + h * 32 + dh] = f2b(accv);
}

__global__ __launch_bounds__(256) void refs_k(const float* __restrict__ r, float* __restrict__ dst){
  int i = blockIdx.x * 256 + threadIdx.x;
  dst[i] = r[i & 8191];
}

// ---------------------------------------------------------------------------
static inline void g64(hipStream_t st, int mode,
    const void* A, int lda, long sA2, long sA1,
    const void* W, int ldw, long sW2, long sW1,
    const float* bias, void* C, int ldo, long sC2, long sC1,
    int M, int N, int K, int Z, int zs)
{
  dim3 g((M + 63) / 64, (N + 63) / 64, Z), b(256, 1, 1);
  switch (mode) {
    case 1: gemm64_k<true, true, true, false,false><<<g,b,0,st>>>(A,lda,sA2,sA1,W,ldw,sW2,sW1,bias,C,ldo,sC2,sC1,M,N,K,zs); break;
    case 2: gemm64_k<true, true, false,false,true ><<<g,b,0,st>>>(A,lda,sA2,sA1,W,ldw,sW2,sW1,bias,C,ldo,sC2,sC1,M,N,K,zs); break;
    case 4: gemm64_k<true, false,true, false,true ><<<g,b,0,st>>>(A,lda,sA2,sA1,W,ldw,sW2,sW1,bias,C,ldo,sC2,sC1,M,N,K,zs); break;
    case 5: gemm64_k<true, false,true, false,false><<<g,b,0,st>>>(A,lda,sA2,sA1,W,ldw,sW2,sW1,bias,C,ldo,sC2,sC1,M,N,K,zs); break;
    case 6: gemm64_k<true, false,true, true, true ><<<g,b,0,st>>>(A,lda,sA2,sA1,W,ldw,sW2,sW1,bias,C,ldo,sC2,sC1,M,N,K,zs); break;
    case 7: gemm64_k<false,false,true, false,true ><<<g,b,0,st>>>(A,lda,sA2,sA1,W,ldw,sW2,sW1,bias,C,ldo,sC2,sC1,M,N,K,zs); break;
  }
}

extern "C" void kernel_launch(void* const* d_in, const int* in_sizes, int n_in,
                              void* d_out, int out_size, void* d_ws, size_t ws_size,
                              hipStream_t stream)
{
  (void)in_sizes; (void)n_in; (void)out_size;
  const float* query = (const float*)d_in[0];
  const float* qpos  = (const float*)d_in[1];
  const float* refp  = (const float*)d_in[2];
  const float* src   = (const float*)d_in[3];
  const float* sa_in_w  = (const float*)d_in[6];
  const float* sa_in_b  = (const float*)d_in[7];
  const float* sa_out_w = (const float*)d_in[8];
  const float* sa_out_b = (const float*)d_in[9];
  const float* off_w = (const float*)d_in[10];
  const float* off_b = (const float*)d_in[11];
  const float* aw_w  = (const float*)d_in[12];
  const float* aw_b  = (const float*)d_in[13];
  const float* val_w = (const float*)d_in[14];
  const float* val_b = (const float*)d_in[15];
  const float* cout_w = (const float*)d_in[16];
  const float* cout_b = (const float*)d_in[17];
  const float* n1w = (const float*)d_in[18]; const float* n1b = (const float*)d_in[19];
  const float* n2w = (const float*)d_in[20]; const float* n2b = (const float*)d_in[21];
  const float* n3w = (const float*)d_in[22]; const float* n3b = (const float*)d_in[23];
  const float* ff1w = (const float*)d_in[24]; const float* ff1b = (const float*)d_in[25];
  const float* ff2w = (const float*)d_in[26]; const float* ff2b = (const float*)d_in[27];

  float* hs = (float*)d_out;
  float* refs_out = hs + (long)6 * 4096 * 256;

  char* base = (char*)d_ws;
  float* out_f = (float*)(base);                  // 4 MB
  float* tmp_f = (float*)(base + (4u << 20));     // 4 MB (Plan B only)
  u16*   qk_b  = (u16*)  (base + (8u << 20));     // 2 MB
  u16*   out_b = (u16*)  (base + (10u << 20));    // 2 MB
  char*  rest  =          base + (12u << 20);

  const size_t NEED_A = 170u << 20;
  const bool planA = (ws_size >= NEED_A);

  init_prep_k<<<4096, 256, 0, stream>>>(query, qpos, out_f, out_b, qk_b);

  if (planA) {
    // bf16 weights (persistent per call)
    u16* wsa_b  = (u16*)(rest);                       // 1179648
    u16* wsao_b = wsa_b  + 1179648;                   // 393216
    u16* wofaw  = wsao_b + 393216;                    // 147456 ([l][96][256])
    u16* wval_b = wofaw  + 147456;                    // 393216
    u16* wcao_b = wval_b + 393216;                    // 393216
    u16* wff1_b = wcao_b + 393216;                    // 1572864
    u16* wff2_b = wff1_b + 1572864;                   // 1572864
    u16* src_b  = wff2_b + 1572864;                   // 30720000
    float* obc  = (float*)(src_b + 30720000);         // 576 fp32 ([l][96])
    char* U = (char*)(obc + 576);
    // SA phase:
    u16* qkbuf = (u16*)(U);                           // 4 MB (4096x512)
    u16* vbuf  = (u16*)(U + (4u << 20));              // 2 MB
    u16* vt    = (u16*)(U + (6u << 20));              // 2 MB
    u16* obuf  = (u16*)(U + (8u << 20));              // 2 MB
    u16* sbuf  = (u16*)(U + (10u << 20));             // 64 MB
    // CA phase (aliases SA region, all consumed):
    float* oawo = (float*)(U);                        // 1.5 MB (4096x96 fp32)
    u16*   mo   = (u16*)  (U + (2u << 20));           // 2 MB
    u16*   vsrc = (u16*)  (U + (4u << 20));           // 58.6 MB (120000x256)
    // FFN phase:
    u16*   ffh  = (u16*)(U);                          // 8 MB

    auto cv = [&](const float* s, u16* d, long nel){
      int n8 = (int)(nel / 8);
      cvt_k<<<(n8 + 255) / 256, 256, 0, stream>>>(s, d, n8);
    };
    cv(sa_in_w,  wsa_b,  1179648); cv(sa_out_w, wsao_b, 393216);
    cv(val_w,    wval_b, 393216);  cv(cout_w,   wcao_b, 393216);
    cv(ff1w,     wff1_b, 1572864); cv(ff2w,     wff2_b, 1572864);
    cv(src,      src_b,  30720000);
    offaw_pack_k<<<579, 256, 0, stream>>>(off_w, aw_w, off_b, aw_b, wofaw, obc);

    for (int l = 0; l < 6; l++){
      const u16* wsa = wsa_b + (long)l * 768 * 256;
      const float* bsa = sa_in_b + l * 768;
      // ---- self attention ----
      gemm_w_k<false,true,false,false><<<dim3(64,2,1),256,0,stream>>>(
          qk_b, 256, wsa, bsa, qkbuf, 512, 4096, 512, 256,
          nullptr, nullptr,nullptr,nullptr,nullptr,nullptr,nullptr,nullptr,nullptr);
      gemm_w_k<false,true,true,false><<<dim3(64,1,1),256,0,stream>>>(
          out_b, 256, wsa + 512*256, bsa + 512, vbuf, 256, 4096, 256, 256,
          vt, nullptr,nullptr,nullptr,nullptr,nullptr,nullptr,nullptr,nullptr);
      g64(stream, 2, qkbuf, 512, 524288, 32, qkbuf + 256, 512, 524288, 32, nullptr,
          sbuf, 1024, 8388608, 1048576, 1024, 1024, 32, 32, 3);          // S = Q K^T
      softmax_k<<<32768, 256, 0, stream>>>(sbuf, 0.17677669529663687f);
      g64(stream, 2, sbuf, 1024, 8388608, 1048576, vt, 1024, 262144, 32768, nullptr,
          obuf, 256, 262144, 32, 1024, 32, 1024, 32, 3);                 // O = P V
      gemm_w_k<false,false,false,true><<<dim3(64,1,1),256,0,stream>>>(   // out-proj + norm2
          obuf, 256, wsao_b + (long)l*65536, sa_out_b + l*256, nullptr, 0, 4096, 256, 256,
          nullptr, out_f, n2w + l*256, n2b + l*256, qpos, out_f, nullptr, qk_b, nullptr);
      // ---- deformable cross attention ----
      g64(stream, 1, qk_b, 256,0,0, wofaw + (long)l*24576, 256,0,0, obc + l*96,
          oawo, 96,0,0, 4096,96,256, 1,0);                               // off|aw proj
      gemm_w_k<false,true,false,false><<<dim3(1875,1,1),256,0,stream>>>( // value proj
          src_b, 256, wval_b + (long)l*65536, val_b + l*256, vsrc, 256, 120000, 256, 256,
          nullptr, nullptr,nullptr,nullptr,nullptr,nullptr,nullptr,nullptr,nullptr);
      msda_k<<<4096, 256, 0, stream>>>(refp, oawo, 96, oawo + 64, 96, vsrc, mo, 0, 7680000);
      gemm_w_k<false,false,false,true><<<dim3(64,1,1),256,0,stream>>>(   // ca-out + norm1
          mo, 256, wcao_b + (long)l*65536, cout_b + l*256, nullptr, 0, 4096, 256, 256,
          nullptr, out_f, n1w + l*256, n1b + l*256, nullptr, out_f, out_b, nullptr, nullptr);
      // ---- ffn ----
      gemm_w_k<true,true,false,false><<<dim3(64,4,1),256,0,stream>>>(    // ff1 + relu
          out_b, 256, wff1_b + (long)l*262144, ff1b + l*1024, ffh, 1024, 4096, 1024, 256,
          nullptr, nullptr,nullptr,nullptr,nullptr,nullptr,nullptr,nullptr,nullptr);
      gemm_w_k<false,false,false,true><<<dim3(64,1,1),256,0,stream>>>(   // ff2 + norm3
          ffh, 1024, wff2_b + (long)l*262144, ff2b + l*256, nullptr, 0, 4096, 256, 1024,
          nullptr, out_f, n3w + l*256, n3b + l*256, qpos, out_f, out_b, qk_b,
          hs + (long)l*1048576);
    }
  } else {
    // -------- PLAN B fallback: round-4 chunked layout --------
    char* U = rest;
    u16* qkbuf = (u16*)(U);
    u16* vbuf  = (u16*)(U + (4u << 20));
    u16* vt    = (u16*)(U + (6u << 20));
    u16* obuf  = (u16*)(U + (8u << 20));
    u16* sbuf  = (u16*)(U + (10u << 20));
    float* offb = (float*)(U);
    float* awbf = (float*)(U + (1u << 20));
    u16*   mo   = (u16*)  (U + (1536u << 10));
    u16*   vsrc = (u16*)  (U + (3584u << 10));
    u16*   ffh  = (u16*)(U);

    for (int l = 0; l < 6; l++){
      const float* wsa = sa_in_w + (long)l * 768 * 256;
      const float* bsa = sa_in_b + l * 768;
      g64(stream, 4, qk_b, 256,0,0, wsa, 256,0,0, bsa, qkbuf, 512,0,0, 4096,512,256, 1,0);
      g64(stream, 4, out_b,256,0,0, wsa + 512*256, 256,0,0, bsa + 512, vbuf, 256,0,0, 4096,256,256, 1,0);
      vt_k<<<4096, 256, 0, stream>>>(vbuf, vt);
      for (int b = 0; b < 4; b++){
        const u16* qb = qkbuf + (long)b * 524288;
        g64(stream, 2, qb, 512, 0, 32, qb + 256, 512, 0, 32, nullptr,
            sbuf, 1024, 0, 1048576, 1024, 1024, 32, 8, 3);
        softmax_k<<<8192, 256, 0, stream>>>(sbuf, 0.17677669529663687f);
        g64(stream, 2, sbuf, 1024, 0, 1048576, vt + (long)b*262144, 1024, 0, 32768, nullptr,
            obuf + (long)b*262144, 256, 0, 32, 1024, 32, 1024, 8, 3);
      }
      g64(stream, 5, obuf, 256,0,0, sa_out_w + (long)l*65536, 256,0,0, sa_out_b + l*256,
          tmp_f, 256,0,0, 4096,256,256, 1,0);
      add_ln_k<true,false,false><<<4096,256,0,stream>>>(tmp_f, n2w+l*256, n2b+l*256, qpos,
          out_f, nullptr, qk_b, nullptr);
      g64(stream, 5, qk_b, 256,0,0, off_w + (long)l*16384, 256,0,0, off_b + l*64,
          offb, 64,0,0, 4096,64,256, 1,0);
      g64(stream, 5, qk_b, 256,0,0, aw_w + (long)l*8192, 256,0,0, aw_b + l*32,
          awbf, 32,0,0, 4096,32,256, 1,0);
      for (int b = 0; b < 4; b++){
        g64(stream, 7, src + (long)b*7680000, 256,0,0, val_w + (long)l*65536, 256,0,0,
            val_b + l*256, vsrc, 256,0,0, 30000,256,256, 1,0);
        msda_k<<<1024, 256, 0, stream>>>(refp, offb, 64, awbf, 32, vsrc, mo, b, 0);
      }
      g64(stream, 5, mo, 256,0,0, cout_w + (long)l*65536, 256,0,0, cout_b + l*256,
          tmp_f, 256,0,0, 4096,256,256, 1,0);
      add_ln_k<false,false,true><<<4096,256,0,stream>>>(tmp_f, n1w+l*256, n1b+l*256, nullptr,
          out_f, out_b, nullptr, nullptr);
      g64(stream, 6, out_b, 256,0,0, ff1w + (long)l*262144, 256,0,0, ff1b + l*1024,
          ffh, 1024,0,0, 4096,1024,256, 1,0);
      g64(stream, 5, ffh, 1024,0,0, ff2w + (long)l*262144, 1024,0,0, ff2b + l*256,
          tmp_f, 256,0,0, 4096,256,1024, 1,0);
      add_ln_k<true,true,true><<<4096,256,0,stream>>>(tmp_f, n3w+l*256, n3b+l*256, qpos,
          out_f, out_b, qk_b, hs + (long)l*1048576);
    }
  }
  refs_k<<<192, 256, 0, stream>>>(refp, refs_out);
}

// Round 6
// 2013.164 us; speedup vs baseline: 2.2636x; 1.0900x over previous
//
#include <hip/hip_runtime.h>

typedef __attribute__((ext_vector_type(8))) short short8;
typedef __attribute__((ext_vector_type(4))) short short4v;
typedef __attribute__((ext_vector_type(4))) float f32x4;
typedef unsigned short u16;

#define DEVI static __device__ __forceinline__

// BS=4 NQ=1024 D=256 NH=8 NP=4 L=6 DFF=1024 H=200 W=150 NV=30000 DH=32
// d_in/d_out are FP32. Internals: bf16 MFMA, fp32 accum, fp32 residual+LN.
DEVI float b2f(u16 u){ unsigned int x = ((unsigned int)u) << 16; float f; __builtin_memcpy(&f, &x, 4); return f; }
DEVI u16 f2b(float f){ unsigned int u; __builtin_memcpy(&u, &f, 4); u += 0x7fffu + ((u >> 16) & 1u); return (u16)(u >> 16); }
DEVI short8 cvt8(const float* __restrict__ p){
  f32x4 a = *(const f32x4*)p;
  f32x4 b = *(const f32x4*)(p + 4);
  short8 r;
  r[0]=(short)f2b(a[0]); r[1]=(short)f2b(a[1]); r[2]=(short)f2b(a[2]); r[3]=(short)f2b(a[3]);
  r[4]=(short)f2b(b[0]); r[5]=(short)f2b(b[1]); r[6]=(short)f2b(b[2]); r[7]=(short)f2b(b[3]);
  return r;
}

__global__ __launch_bounds__(256) void cvt_k(const float* __restrict__ s, u16* __restrict__ d, int n8){
  int i = blockIdx.x * 256 + threadIdx.x;
  if (i < n8) ((short8*)d)[i] = cvt8(s + (long)i * 8);
}

// pack off_w|aw_w -> wofaw (bf16, [l][96][256]) and off_b|aw_b -> obc (fp32, [l][96])
__global__ __launch_bounds__(256) void offaw_pack_k(
    const float* __restrict__ off_w, const float* __restrict__ aw_w,
    const float* __restrict__ off_b, const float* __restrict__ aw_b,
    u16* __restrict__ wofaw, float* __restrict__ obc)
{
  int tid = blockIdx.x * 256 + threadIdx.x;
  if (tid < 98304) {
    int l = tid / 16384, rem = tid - l * 16384;
    wofaw[l * 24576 + rem] = f2b(off_w[tid]);
  } else if (tid < 147456) {
    int t2 = tid - 98304;
    int l = t2 / 8192, rem = t2 - l * 8192;
    wofaw[l * 24576 + 16384 + rem] = f2b(aw_w[t2]);
  } else if (tid < 147840) {
    int t3 = tid - 147456;
    obc[(t3 / 64) * 96 + (t3 % 64)] = off_b[t3];
  } else if (tid < 148032) {
    int t4 = tid - 147840;
    obc[(t4 / 32) * 96 + 64 + (t4 % 32)] = aw_b[t4];
  }
}

// ---------------------------------------------------------------------------
// Flash self-attention: one block per (b, h, q-tile of 128). 4 waves, each
// owns 32 q-rows. K processed in 8 tiles of 128. DH=32 = one MFMA K-depth.
// Q,K from qkbuf [4096][512] (Q cols 0..255, K cols 256..511, head-major);
// V from vt [b][h][32 dh][1024 q]. Online softmax (fp32 stats), P via
// per-wave LDS patch (m120 transform), O = (1/l) * sum P V -> obuf bf16.
// ---------------------------------------------------------------------------
__global__ __launch_bounds__(256) void flash_k(
    const u16* __restrict__ qkbuf, const u16* __restrict__ vt,
    u16* __restrict__ obuf)
{
  const float SC = 0.17677669529663687f;   // 1/sqrt(32)
  __shared__ u16 Plds[4][32][136];         // per-wave P patch (32 q x 128 k)
  const int bh = blockIdx.x >> 3;          // b*8 + h
  const int b = bh >> 3, h = bh & 7;
  const int qt = blockIdx.x & 7;
  const int wave = threadIdx.x >> 6, lane = threadIdx.x & 63;
  const int lr = lane & 15, lq = lane >> 4;
  const int qbase = qt * 128 + wave * 32;

  // Q fragments (A-layout: m=lr, k=lq*8..): row qbase+i*16+lr, dh = lq*8..+7
  short8 qf[2];
#pragma unroll
  for (int i = 0; i < 2; i++)
    qf[i] = *(const short8*)(qkbuf + (long)(b * 1024 + qbase + i * 16 + lr) * 512 + h * 32 + lq * 8);

  const u16* Kb = qkbuf + (long)b * 1024 * 512 + 256 + h * 32;
  const u16* Vb = vt + (long)bh * 32 * 1024;

  f32x4 acc_o[2][2] = {};
  float m_run[2][4], l_run[2][4];
#pragma unroll
  for (int i = 0; i < 2; i++)
#pragma unroll
    for (int r = 0; r < 4; r++){ m_run[i][r] = -3e38f; l_run[i][r] = 0.f; }

  for (int kt = 0; kt < 8; kt++) {
    // ---- S = Q K^T for this 128-col tile ----
    f32x4 s[2][8] = {};
#pragma unroll
    for (int j = 0; j < 8; j++) {
      short8 kf = *(const short8*)(Kb + (long)(kt * 128 + j * 16 + lr) * 512 + lq * 8);
#pragma unroll
      for (int i = 0; i < 2; i++)
        s[i][j] = __builtin_amdgcn_mfma_f32_16x16x32_bf16(qf[i], kf, s[i][j], 0, 0, 0);
    }
    // ---- online softmax per q-row (row = i*16 + lq*4 + r, cols j*16+lr) ----
#pragma unroll
    for (int i = 0; i < 2; i++) {
#pragma unroll
      for (int r = 0; r < 4; r++) {
        float mx = s[i][0][r];
#pragma unroll
        for (int j = 1; j < 8; j++) mx = fmaxf(mx, s[i][j][r]);
#pragma unroll
        for (int m = 1; m <= 8; m <<= 1) mx = fmaxf(mx, __shfl_xor(mx, m));
        float m_new = fmaxf(m_run[i][r], mx);
        float alpha = __expf((m_run[i][r] - m_new) * SC);
        float sum = 0.f;
        int row = i * 16 + lq * 4 + r;
#pragma unroll
        for (int j = 0; j < 8; j++) {
          float p = __expf((s[i][j][r] - m_new) * SC);
          sum += p;
          Plds[wave][row][j * 16 + lr] = f2b(p);
        }
#pragma unroll
        for (int m = 1; m <= 8; m <<= 1) sum += __shfl_xor(sum, m);
        l_run[i][r] = l_run[i][r] * alpha + sum;
        m_run[i][r] = m_new;
#pragma unroll
        for (int d = 0; d < 2; d++) acc_o[i][d][r] *= alpha;
      }
    }
    // ---- O += P V (per-wave LDS patch; same-wave ds order handled by waitcnt) ----
#pragma unroll
    for (int kc = 0; kc < 4; kc++) {
      short8 pf[2];
#pragma unroll
      for (int i = 0; i < 2; i++)
        pf[i] = *(const short8*)&Plds[wave][i * 16 + lr][kc * 32 + lq * 8];
#pragma unroll
      for (int d = 0; d < 2; d++) {
        short8 vf = *(const short8*)(Vb + (long)(d * 16 + lr) * 1024 + kt * 128 + kc * 32 + lq * 8);
#pragma unroll
        for (int i = 0; i < 2; i++)
          acc_o[i][d] = __builtin_amdgcn_mfma_f32_16x16x32_bf16(pf[i], vf, acc_o[i][d], 0, 0, 0);
      }
    }
  }
  // ---- epilogue: O/l -> obuf[(b,q)][h*32+dh] ----
#pragma unroll
  for (int i = 0; i < 2; i++) {
#pragma unroll
    for (int r = 0; r < 4; r++) {
      float inv = 1.f / l_run[i][r];
      int q = qbase + i * 16 + lq * 4 + r;
#pragma unroll
      for (int d = 0; d < 2; d++)
        obuf[(long)(b * 1024 + q) * 256 + h * 32 + d * 16 + lr] = f2b(acc_o[i][d][r] * inv);
    }
  }
}

// ---------------------------------------------------------------------------
// gemm_w_k: 64(M) x 256(N) block; 4 waves side-by-side. A chunk staged in LDS
// via global_load_lds; W streamed (L2). Optional RELU/bf16-out/fused V^T/
// fused residual+LayerNorm epilogue.
// ---------------------------------------------------------------------------
template<bool RELU, bool OUTBF, bool VT, bool LN>
__global__ __launch_bounds__(256) void gemm_w_k(
    const u16* __restrict__ A, int lda,
    const u16* __restrict__ W,
    const float* __restrict__ bias,
    void* __restrict__ Cv, int ldo,
    int M, int N, int K,
    u16* __restrict__ vt,
    const float* __restrict__ res,
    const float* __restrict__ lnw, const float* __restrict__ lnb,
    const float* __restrict__ qpos,
    float* __restrict__ out_f, u16* __restrict__ out_b16,
    u16* __restrict__ qk_b16, float* __restrict__ hsp)
{
  __shared__ u16 As[32][64][8];
  __shared__ float r1s[4][64], r2s[4][64], mArr[64], iArr[64];
  const int wave = threadIdx.x >> 6, lane = threadIdx.x & 63;
  const int bm = blockIdx.x * 64;
  const int bn = blockIdx.y * 256 + wave * 64;
  const int lr = lane & 15, lq = lane >> 4;
  f32x4 acc[4][4] = {};
  const int nchunks = K >> 8;
  for (int ch = 0; ch < nchunks; ch++) {
    const u16* ga = A + (long)(bm + lane) * lda + ch * 256;
#pragma unroll
    for (int g = 0; g < 8; g++) {
      int kgrp = wave * 8 + g;
      __builtin_amdgcn_global_load_lds(
          (const __attribute__((address_space(1))) void*)(ga + kgrp * 8),
          (__attribute__((address_space(3))) void*)&As[kgrp][0][0], 16, 0, 0);
    }
    __syncthreads();
#pragma unroll
    for (int s = 0; s < 8; s++) {
      short8 af[4], bf[4];
#pragma unroll
      for (int i = 0; i < 4; i++)
        af[i] = *(const short8*)&As[s * 4 + lq][i * 16 + lr][0];
#pragma unroll
      for (int j = 0; j < 4; j++) {
        int cc = bn + j * 16 + lr;
        bf[j] = *(const short8*)(W + (long)cc * K + ch * 256 + s * 32 + lq * 8);
      }
#pragma unroll
      for (int i = 0; i < 4; i++)
#pragma unroll
        for (int j = 0; j < 4; j++)
          acc[i][j] = __builtin_amdgcn_mfma_f32_16x16x32_bf16(af[i], bf[j], acc[i][j], 0, 0, 0);
    }
    __syncthreads();
  }

  float bv[4];
#pragma unroll
  for (int j = 0; j < 4; j++) bv[j] = bias[bn + j * 16 + lr];

  if (!LN) {
#pragma unroll
    for (int j = 0; j < 4; j++) {
      int cc = bn + j * 16 + lr;
#pragma unroll
      for (int i = 0; i < 4; i++) {
#pragma unroll
        for (int r = 0; r < 4; r++) {
          int rr = bm + i * 16 + lq * 4 + r;
          float v = acc[i][j][r] + bv[j];
          if (RELU) v = fmaxf(v, 0.f);
          long idx = (long)rr * ldo + cc;
          if (OUTBF) ((u16*)Cv)[idx] = f2b(v);
          else       ((float*)Cv)[idx] = v;
          if (VT) {
            int b_ = rr >> 10, q_ = rr & 1023, h_ = cc >> 5, dh_ = cc & 31;
            vt[(long)((((b_ << 3) + h_) << 5) + dh_) * 1024 + q_] = f2b(v);
          }
        }
      }
    }
  } else {
    float s1[4][4] = {}, s2[4][4] = {};
#pragma unroll
    for (int i = 0; i < 4; i++) {
#pragma unroll
      for (int r = 0; r < 4; r++) {
        int rowg = bm + i * 16 + lq * 4 + r;
#pragma unroll
        for (int j = 0; j < 4; j++) {
          int cc = bn + j * 16 + lr;
          float x = acc[i][j][r] + bv[j] + res[(long)rowg * 256 + cc];
          s1[i][r] += x; s2[i][r] += x * x;
        }
      }
    }
#pragma unroll
    for (int i = 0; i < 4; i++)
#pragma unroll
      for (int r = 0; r < 4; r++) {
#pragma unroll
        for (int m = 1; m <= 8; m <<= 1) {
          s1[i][r] += __shfl_xor(s1[i][r], m);
          s2[i][r] += __shfl_xor(s2[i][r], m);
        }
      }
    if (lr == 0) {
#pragma unroll
      for (int i = 0; i < 4; i++)
#pragma unroll
        for (int r = 0; r < 4; r++) {
          int rl = i * 16 + lq * 4 + r;
          r1s[wave][rl] = s1[i][r];
          r2s[wave][rl] = s2[i][r];
        }
    }
    __syncthreads();
    if (threadIdx.x < 64) {
      int t = threadIdx.x;
      float a = r1s[0][t] + r1s[1][t] + r1s[2][t] + r1s[3][t];
      float b = r2s[0][t] + r2s[1][t] + r2s[2][t] + r2s[3][t];
      float m = a * (1.f / 256.f);
      float var = b * (1.f / 256.f) - m * m;
      mArr[t] = m;
      iArr[t] = rsqrtf(var + 1e-5f);
    }
    __syncthreads();
#pragma unroll
    for (int i = 0; i < 4; i++) {
#pragma unroll
      for (int r = 0; r < 4; r++) {
        int rl = i * 16 + lq * 4 + r;
        int rowg = bm + rl;
        float m = mArr[rl], inv = iArr[rl];
#pragma unroll
        for (int j = 0; j < 4; j++) {
          int cc = bn + j * 16 + lr;
          long idx = (long)rowg * 256 + cc;
          float x = acc[i][j][r] + bv[j] + res[idx];
          float y = (x - m) * inv * lnw[cc] + lnb[cc];
          out_f[idx] = y;
          if (out_b16) out_b16[idx] = f2b(y);
          if (qk_b16)  qk_b16[idx]  = f2b(y + qpos[idx]);
          if (hsp)     hsp[idx]     = y;
        }
      }
    }
  }
}

// ---------------------------------------------------------------------------
// gemm64_k: 64x64 block, direct loads (offaw + Plan-B fallback).
// ---------------------------------------------------------------------------
template<bool ABF, bool WBF, bool BIAS, bool RELU, bool OUTBF>
__global__ __launch_bounds__(256) void gemm64_k(
    const void* __restrict__ Av, int lda, long sA2, long sA1,
    const void* __restrict__ Wv, int ldw, long sW2, long sW1,
    const float* __restrict__ bias,
    void* __restrict__ Cv, int ldo, long sC2, long sC1,
    int M, int N, int K, int zshift)
{
  const int z  = blockIdx.z;
  const int z2 = z >> zshift, z1 = z - (z2 << zshift);
  const long aoff = z2 * sA2 + z1 * sA1;
  const long woff = z2 * sW2 + z1 * sW1;
  const long coff = z2 * sC2 + z1 * sC1;
  const int wave = threadIdx.x >> 6, lane = threadIdx.x & 63;
  const int wm = wave >> 1, wn = wave & 1;
  const int bm = blockIdx.x * 64 + wm * 32;
  const int bn = blockIdx.y * 64 + wn * 32;
  const int lr = lane & 15, lq = lane >> 4;
  const int koff = lq * 8;
  f32x4 acc[2][2] = {};
  const short8 Z8 = {0,0,0,0,0,0,0,0};
  for (int k0 = 0; k0 < K; k0 += 32) {
    short8 af[2], bf[2];
#pragma unroll
    for (int i = 0; i < 2; i++) {
      int r = bm + i * 16 + lr;
      if (r < M) {
        long o = aoff + (long)r * lda + k0 + koff;
        af[i] = ABF ? *(const short8*)((const u16*)Av + o) : cvt8((const float*)Av + o);
      } else af[i] = Z8;
    }
#pragma unroll
    for (int j = 0; j < 2; j++) {
      int c = bn + j * 16 + lr;
      if (c < N) {
        long o = woff + (long)c * ldw + k0 + koff;
        bf[j] = WBF ? *(const short8*)((const u16*)Wv + o) : cvt8((const float*)Wv + o);
      } else bf[j] = Z8;
    }
#pragma unroll
    for (int i = 0; i < 2; i++)
#pragma unroll
      for (int j = 0; j < 2; j++)
        acc[i][j] = __builtin_amdgcn_mfma_f32_16x16x32_bf16(af[i], bf[j], acc[i][j], 0, 0, 0);
  }
#pragma unroll
  for (int j = 0; j < 2; j++) {
    int cc = bn + j * 16 + lr;
    if (cc >= N) continue;
    float bv = BIAS ? bias[cc] : 0.f;
#pragma unroll
    for (int i = 0; i < 2; i++) {
#pragma unroll
      for (int r = 0; r < 4; r++) {
        int rr = bm + i * 16 + lq * 4 + r;
        if (rr >= M) continue;
        float v = acc[i][j][r] + bv;
        if (RELU) v = fmaxf(v, 0.f);
        long idx = coff + (long)rr * ldo + cc;
        if (OUTBF) ((u16*)Cv)[idx] = f2b(v);
        else       ((float*)Cv)[idx] = v;
      }
    }
  }
}

__global__ __launch_bounds__(256) void init_prep_k(const float* __restrict__ q, const float* __restrict__ qpos,
                                                   float* __restrict__ out_f, u16* __restrict__ out_b,
                                                   u16* __restrict__ qk_b){
  long i = (long)blockIdx.x * 256 + threadIdx.x;
  float o = q[i];
  out_f[i] = o;
  out_b[i] = f2b(o);
  qk_b[i]  = f2b(o + qpos[i]);
}

// Plan B only
__global__ __launch_bounds__(256) void vt_k(const u16* __restrict__ V, u16* __restrict__ Vt){
  int tid = blockIdx.x * 256 + threadIdx.x;
  int q = tid & 1023;
  int rest = tid >> 10;
  int dh = rest & 31, h = (rest >> 5) & 7, b = rest >> 8;
  Vt[tid] = V[(long)((b << 10) + q) * 256 + (h << 5) + dh];
}

__global__ __launch_bounds__(256) void softmax_k(u16* __restrict__ S, float scale){
  long row = blockIdx.x;
  u16* p = S + row * 1024;
  int t = threadIdx.x;
  short4v sv = *(short4v*)(p + t * 4);
  float v[4]; float mx = -1e30f;
#pragma unroll
  for (int i = 0; i < 4; i++){ v[i] = b2f((u16)sv[i]); mx = fmaxf(mx, v[i]); }
  __shared__ float red[256];
  red[t] = mx; __syncthreads();
  for (int s = 128; s > 0; s >>= 1){ if (t < s) red[t] = fmaxf(red[t], red[t + s]); __syncthreads(); }
  mx = red[0]; __syncthreads();
  float sum = 0.f;
#pragma unroll
  for (int i = 0; i < 4; i++){ v[i] = __expf((v[i] - mx) * scale); sum += v[i]; }
  red[t] = sum; __syncthreads();
  for (int s = 128; s > 0; s >>= 1){ if (t < s) red[t] += red[t + s]; __syncthreads(); }
  float inv = 1.f / red[0];
#pragma unroll
  for (int i = 0; i < 4; i++) sv[i] = (short)f2b(v[i] * inv);
  *(short4v*)(p + t * 4) = sv;
}

template<bool QKPOS, bool HS, bool OUTB>
__global__ __launch_bounds__(256) void add_ln_k(
    const float* __restrict__ sub,
    const float* __restrict__ w, const float* __restrict__ b,
    const float* __restrict__ qpos,
    float* __restrict__ out_f, u16* __restrict__ out_b,
    u16* __restrict__ qk_b, float* __restrict__ hs)
{
  int row = blockIdx.x, t = threadIdx.x;
  long idx = (long)row * 256 + t;
  float x = out_f[idx] + sub[idx];
  __shared__ float r1[256], r2[256];
  r1[t] = x; r2[t] = x * x; __syncthreads();
  for (int s = 128; s > 0; s >>= 1){ if (t < s){ r1[t] += r1[t + s]; r2[t] += r2[t + s]; } __syncthreads(); }
  float m = r1[0] * (1.f / 256.f);
  float var = r2[0] * (1.f / 256.f) - m * m;
  float y = (x - m) * rsqrtf(var + 1e-5f) * w[t] + b[t];
  out_f[idx] = y;
  if (OUTB)  out_b[idx] = f2b(y);
  if (QKPOS) qk_b[idx]  = f2b(y + qpos[idx]);
  if (HS)    hs[idx]    = y;
}

__global__ __launch_bounds__(256) void msda_k(
    const float* __restrict__ refp,
    const float* __restrict__ off, int ldoff,
    const float* __restrict__ aw, int ldaw,
    const u16* __restrict__ v,
    u16* __restrict__ o,
    int bbase, long vstride)
{
  int tid = blockIdx.x * 256 + threadIdx.x;
  int dh = tid & 31;
  int h  = (tid >> 5) & 7;
  int qq = tid >> 8;
  int bq = (bbase << 10) + qq;
  int b  = bq >> 10;
  float rx = refp[bq * 2 + 0];
  float ry = refp[bq * 2 + 1];
  const float* offp = off + (long)bq * ldoff + h * 8;
  const float* awp  = aw  + (long)bq * ldaw + h * 4;
  float a0 = awp[0], a1 = awp[1], a2 = awp[2], a3 = awp[3];
  float am = fmaxf(fmaxf(a0, a1), fmaxf(a2, a3));
  float e[4];
  e[0] = __expf(a0 - am); e[1] = __expf(a1 - am); e[2] = __expf(a2 - am); e[3] = __expf(a3 - am);
  float einv = 1.f / (e[0] + e[1] + e[2] + e[3]);
  const u16* vb = v + b * vstride + h * 32 + dh;
  float accv = 0.f;
#pragma unroll
  for (int pp = 0; pp < 4; pp++){
    float x = rx * 150.f + offp[pp * 2 + 0] - 0.5f;
    float y = ry * 200.f + offp[pp * 2 + 1] - 0.5f;
    float x0 = floorf(x), y0 = floorf(y);
    float s = 0.f;
#pragma unroll
    for (int c = 0; c < 4; c++){
      int dx = c & 1, dy = c >> 1;
      float xi = x0 + dx, yi = y0 + dy;
      float wt = (1.f - fabsf(x - xi)) * (1.f - fabsf(y - yi));
      if (xi >= 0.f && xi < 150.f && yi >= 0.f && yi < 200.f && wt > 0.f) {
        int xc = (int)xi, yc = (int)yi;
        s += wt * b2f(vb[((long)yc * 150 + xc) * 256]);
      }
    }
    accv += e[pp] * einv * s;
  }
  o[(long)bq * 256 + h * 32 + dh] = f2b(accv);
}

__global__ __launch_bounds__(256) void refs_k(const float* __restrict__ r, float* __restrict__ dst){
  int i = blockIdx.x * 256 + threadIdx.x;
  dst[i] = r[i & 8191];
}

// ---------------------------------------------------------------------------
static inline void g64(hipStream_t st, int mode,
    const void* A, int lda, long sA2, long sA1,
    const void* W, int ldw, long sW2, long sW1,
    const float* bias, void* C, int ldo, long sC2, long sC1,
    int M, int N, int K, int Z, int zs)
{
  dim3 g((M + 63) / 64, (N + 63) / 64, Z), b(256, 1, 1);
  switch (mode) {
    case 1: gemm64_k<true, true, true, false,false><<<g,b,0,st>>>(A,lda,sA2,sA1,W,ldw,sW2,sW1,bias,C,ldo,sC2,sC1,M,N,K,zs); break;
    case 2: gemm64_k<true, true, false,false,true ><<<g,b,0,st>>>(A,lda,sA2,sA1,W,ldw,sW2,sW1,bias,C,ldo,sC2,sC1,M,N,K,zs); break;
    case 4: gemm64_k<true, false,true, false,true ><<<g,b,0,st>>>(A,lda,sA2,sA1,W,ldw,sW2,sW1,bias,C,ldo,sC2,sC1,M,N,K,zs); break;
    case 5: gemm64_k<true, false,true, false,false><<<g,b,0,st>>>(A,lda,sA2,sA1,W,ldw,sW2,sW1,bias,C,ldo,sC2,sC1,M,N,K,zs); break;
    case 6: gemm64_k<true, false,true, true, true ><<<g,b,0,st>>>(A,lda,sA2,sA1,W,ldw,sW2,sW1,bias,C,ldo,sC2,sC1,M,N,K,zs); break;
    case 7: gemm64_k<false,false,true, false,true ><<<g,b,0,st>>>(A,lda,sA2,sA1,W,ldw,sW2,sW1,bias,C,ldo,sC2,sC1,M,N,K,zs); break;
  }
}

extern "C" void kernel_launch(void* const* d_in, const int* in_sizes, int n_in,
                              void* d_out, int out_size, void* d_ws, size_t ws_size,
                              hipStream_t stream)
{
  (void)in_sizes; (void)n_in; (void)out_size;
  const float* query = (const float*)d_in[0];
  const float* qpos  = (const float*)d_in[1];
  const float* refp  = (const float*)d_in[2];
  const float* src   = (const float*)d_in[3];
  const float* sa_in_w  = (const float*)d_in[6];
  const float* sa_in_b  = (const float*)d_in[7];
  const float* sa_out_w = (const float*)d_in[8];
  const float* sa_out_b = (const float*)d_in[9];
  const float* off_w = (const float*)d_in[10];
  const float* off_b = (const float*)d_in[11];
  const float* aw_w  = (const float*)d_in[12];
  const float* aw_b  = (const float*)d_in[13];
  const float* val_w = (const float*)d_in[14];
  const float* val_b = (const float*)d_in[15];
  const float* cout_w = (const float*)d_in[16];
  const float* cout_b = (const float*)d_in[17];
  const float* n1w = (const float*)d_in[18]; const float* n1b = (const float*)d_in[19];
  const float* n2w = (const float*)d_in[20]; const float* n2b = (const float*)d_in[21];
  const float* n3w = (const float*)d_in[22]; const float* n3b = (const float*)d_in[23];
  const float* ff1w = (const float*)d_in[24]; const float* ff1b = (const float*)d_in[25];
  const float* ff2w = (const float*)d_in[26]; const float* ff2b = (const float*)d_in[27];

  float* hs = (float*)d_out;
  float* refs_out = hs + (long)6 * 4096 * 256;

  char* base = (char*)d_ws;
  float* out_f = (float*)(base);                  // 4 MB
  float* tmp_f = (float*)(base + (4u << 20));     // 4 MB (Plan B only)
  u16*   qk_b  = (u16*)  (base + (8u << 20));     // 2 MB
  u16*   out_b = (u16*)  (base + (10u << 20));    // 2 MB
  char*  rest  =          base + (12u << 20);

  const size_t NEED_A = 170u << 20;
  const bool planA = (ws_size >= NEED_A);

  init_prep_k<<<4096, 256, 0, stream>>>(query, qpos, out_f, out_b, qk_b);

  if (planA) {
    u16* wsa_b  = (u16*)(rest);                       // 1179648
    u16* wsao_b = wsa_b  + 1179648;                   // 393216
    u16* wofaw  = wsao_b + 393216;                    // 147456
    u16* wval_b = wofaw  + 147456;                    // 393216
    u16* wcao_b = wval_b + 393216;                    // 393216
    u16* wff1_b = wcao_b + 393216;                    // 1572864
    u16* wff2_b = wff1_b + 1572864;                   // 1572864
    u16* src_b  = wff2_b + 1572864;                   // 30720000
    float* obc  = (float*)(src_b + 30720000);         // 576
    char* U = (char*)(obc + 576);
    // SA phase:
    u16* qkbuf = (u16*)(U);                           // 4 MB (4096x512)
    u16* vbuf  = (u16*)(U + (4u << 20));              // 2 MB
    u16* vt    = (u16*)(U + (6u << 20));              // 2 MB
    u16* obuf  = (u16*)(U + (8u << 20));              // 2 MB
    // CA phase (aliases SA region, all consumed):
    float* oawo = (float*)(U);                        // 1.5 MB
    u16*   mo   = (u16*)  (U + (2u << 20));           // 2 MB
    u16*   vsrc = (u16*)  (U + (4u << 20));           // 58.6 MB
    // FFN phase:
    u16*   ffh  = (u16*)(U);                          // 8 MB

    auto cv = [&](const float* s, u16* d, long nel){
      int n8 = (int)(nel / 8);
      cvt_k<<<(n8 + 255) / 256, 256, 0, stream>>>(s, d, n8);
    };
    cv(sa_in_w,  wsa_b,  1179648); cv(sa_out_w, wsao_b, 393216);
    cv(val_w,    wval_b, 393216);  cv(cout_w,   wcao_b, 393216);
    cv(ff1w,     wff1_b, 1572864); cv(ff2w,     wff2_b, 1572864);
    cv(src,      src_b,  30720000);
    offaw_pack_k<<<579, 256, 0, stream>>>(off_w, aw_w, off_b, aw_b, wofaw, obc);

    for (int l = 0; l < 6; l++){
      const u16* wsa = wsa_b + (long)l * 768 * 256;
      const float* bsa = sa_in_b + l * 768;
      // ---- self attention (flash) ----
      gemm_w_k<false,true,false,false><<<dim3(64,2,1),256,0,stream>>>(
          qk_b, 256, wsa, bsa, qkbuf, 512, 4096, 512, 256,
          nullptr, nullptr,nullptr,nullptr,nullptr,nullptr,nullptr,nullptr,nullptr);
      gemm_w_k<false,true,true,false><<<dim3(64,1,1),256,0,stream>>>(
          out_b, 256, wsa + 512*256, bsa + 512, vbuf, 256, 4096, 256, 256,
          vt, nullptr,nullptr,nullptr,nullptr,nullptr,nullptr,nullptr,nullptr);
      flash_k<<<256, 256, 0, stream>>>(qkbuf, vt, obuf);
      gemm_w_k<false,false,false,true><<<dim3(64,1,1),256,0,stream>>>(   // out-proj + norm2
          obuf, 256, wsao_b + (long)l*65536, sa_out_b + l*256, nullptr, 0, 4096, 256, 256,
          nullptr, out_f, n2w + l*256, n2b + l*256, qpos, out_f, nullptr, qk_b, nullptr);
      // ---- deformable cross attention ----
      g64(stream, 1, qk_b, 256,0,0, wofaw + (long)l*24576, 256,0,0, obc + l*96,
          oawo, 96,0,0, 4096,96,256, 1,0);
      gemm_w_k<false,true,false,false><<<dim3(1875,1,1),256,0,stream>>>( // value proj
          src_b, 256, wval_b + (long)l*65536, val_b + l*256, vsrc, 256, 120000, 256, 256,
          nullptr, nullptr,nullptr,nullptr,nullptr,nullptr,nullptr,nullptr,nullptr);
      msda_k<<<4096, 256, 0, stream>>>(refp, oawo, 96, oawo + 64, 96, vsrc, mo, 0, 7680000);
      gemm_w_k<false,false,false,true><<<dim3(64,1,1),256,0,stream>>>(   // ca-out + norm1
          mo, 256, wcao_b + (long)l*65536, cout_b + l*256, nullptr, 0, 4096, 256, 256,
          nullptr, out_f, n1w + l*256, n1b + l*256, nullptr, out_f, out_b, nullptr, nullptr);
      // ---- ffn ----
      gemm_w_k<true,true,false,false><<<dim3(64,4,1),256,0,stream>>>(
          out_b, 256, wff1_b + (long)l*262144, ff1b + l*1024, ffh, 1024, 4096, 1024, 256,
          nullptr, nullptr,nullptr,nullptr,nullptr,nullptr,nullptr,nullptr,nullptr);
      gemm_w_k<false,false,false,true><<<dim3(64,1,1),256,0,stream>>>(   // ff2 + norm3
          ffh, 1024, wff2_b + (long)l*262144, ff2b + l*256, nullptr, 0, 4096, 256, 1024,
          nullptr, out_f, n3w + l*256, n3b + l*256, qpos, out_f, out_b, qk_b,
          hs + (long)l*1048576);
    }
  } else {
    // -------- PLAN B fallback: round-4 chunked layout --------
    char* U = rest;
    u16* qkbuf = (u16*)(U);
    u16* vbuf  = (u16*)(U + (4u << 20));
    u16* vt    = (u16*)(U + (6u << 20));
    u16* obuf  = (u16*)(U + (8u << 20));
    u16* sbuf  = (u16*)(U + (10u << 20));
    float* offb = (float*)(U);
    float* awbf = (float*)(U + (1u << 20));
    u16*   mo   = (u16*)  (U + (1536u << 10));
    u16*   vsrc = (u16*)  (U + (3584u << 10));
    u16*   ffh  = (u16*)(U);

    for (int l = 0; l < 6; l++){
      const float* wsa = sa_in_w + (long)l * 768 * 256;
      const float* bsa = sa_in_b + l * 768;
      g64(stream, 4, qk_b, 256,0,0, wsa, 256,0,0, bsa, qkbuf, 512,0,0, 4096,512,256, 1,0);
      g64(stream, 4, out_b,256,0,0, wsa + 512*256, 256,0,0, bsa + 512, vbuf, 256,0,0, 4096,256,256, 1,0);
      vt_k<<<4096, 256, 0, stream>>>(vbuf, vt);
      for (int b = 0; b < 4; b++){
        const u16* qb = qkbuf + (long)b * 524288;
        g64(stream, 2, qb, 512, 0, 32, qb + 256, 512, 0, 32, nullptr,
            sbuf, 1024, 0, 1048576, 1024, 1024, 32, 8, 3);
        softmax_k<<<8192, 256, 0, stream>>>(sbuf, 0.17677669529663687f);
        g64(stream, 2, sbuf, 1024, 0, 1048576, vt + (long)b*262144, 1024, 0, 32768, nullptr,
            obuf + (long)b*262144, 256, 0, 32, 1024, 32, 1024, 8, 3);
      }
      g64(stream, 5, obuf, 256,0,0, sa_out_w + (long)l*65536, 256,0,0, sa_out_b + l*256,
          tmp_f, 256,0,0, 4096,256,256, 1,0);
      add_ln_k<true,false,false><<<4096,256,0,stream>>>(tmp_f, n2w+l*256, n2b+l*256, qpos,
          out_f, nullptr, qk_b, nullptr);
      g64(stream, 5, qk_b, 256,0,0, off_w + (long)l*16384, 256,0,0, off_b + l*64,
          offb, 64,0,0, 4096,64,256, 1,0);
      g64(stream, 5, qk_b, 256,0,0, aw_w + (long)l*8192, 256,0,0, aw_b + l*32,
          awbf, 32,0,0, 4096,32,256, 1,0);
      for (int b = 0; b < 4; b++){
        g64(stream, 7, src + (long)b*7680000, 256,0,0, val_w + (long)l*65536, 256,0,0,
            val_b + l*256, vsrc, 256,0,0, 30000,256,256, 1,0);
        msda_k<<<1024, 256, 0, stream>>>(refp, offb, 64, awbf, 32, vsrc, mo, b, 0);
      }
      g64(stream, 5, mo, 256,0,0, cout_w + (long)l*65536, 256,0,0, cout_b + l*256,
          tmp_f, 256,0,0, 4096,256,256, 1,0);
      add_ln_k<false,false,true><<<4096,256,0,stream>>>(tmp_f, n1w+l*256, n1b+l*256, nullptr,
          out_f, out_b, nullptr, nullptr);
      g64(stream, 6, out_b, 256,0,0, ff1w + (long)l*262144, 256,0,0, ff1b + l*1024,
          ffh, 1024,0,0, 4096,1024,256, 1,0);
      g64(stream, 5, ffh, 1024,0,0, ff2w + (long)l*262144, 1024,0,0, ff2b + l*256,
          tmp_f, 256,0,0, 4096,256,1024, 1,0);
      add_ln_k<true,true,true><<<4096,256,0,stream>>>(tmp_f, n3w+l*256, n3b+l*256, qpos,
          out_f, out_b, qk_b, hs + (long)l*1048576);
    }
  }
  refs_k<<<192, 256, 0, stream>>>(refp, refs_out);
}

// Round 7
// 1707.365 us; speedup vs baseline: 2.6690x; 1.1791x over previous
//
#include <hip/hip_runtime.h>

typedef __attribute__((ext_vector_type(8))) short short8;
typedef __attribute__((ext_vector_type(4))) float f32x4;
typedef unsigned short u16;

#define DEVI static __device__ __forceinline__

// BS=4 NQ=1024 D=256 NH=8 NP=4 L=6 DFF=1024 H=200 W=150 NV=30000 DH=32
// d_in/d_out are FP32. Internals: bf16 MFMA, fp32 accum, fp32 residual+LN.
DEVI float b2f(u16 u){ unsigned int x = ((unsigned int)u) << 16; float f; __builtin_memcpy(&f, &x, 4); return f; }
DEVI u16 f2b(float f){ unsigned int u; __builtin_memcpy(&u, &f, 4); u += 0x7fffu + ((u >> 16) & 1u); return (u16)(u >> 16); }
DEVI short8 cvt8(const float* __restrict__ p){
  f32x4 a = *(const f32x4*)p;
  f32x4 b = *(const f32x4*)(p + 4);
  short8 r;
  r[0]=(short)f2b(a[0]); r[1]=(short)f2b(a[1]); r[2]=(short)f2b(a[2]); r[3]=(short)f2b(a[3]);
  r[4]=(short)f2b(b[0]); r[5]=(short)f2b(b[1]); r[6]=(short)f2b(b[2]); r[7]=(short)f2b(b[3]);
  return r;
}

// ---------------------------------------------------------------------------
// One-shot convert/pack of ALL fp32 params -> bf16 (plus obc fp32 pack).
// Unit = 8 elements. Segment sizes in units; see launcher for grid math.
// ---------------------------------------------------------------------------
__global__ __launch_bounds__(256) void cvtall_k(
    const float* __restrict__ sa_in_w, const float* __restrict__ sa_out_w,
    const float* __restrict__ val_w,   const float* __restrict__ cout_w,
    const float* __restrict__ ff1w,    const float* __restrict__ ff2w,
    const float* __restrict__ off_w,   const float* __restrict__ aw_w,
    const float* __restrict__ off_b,   const float* __restrict__ aw_b,
    const float* __restrict__ src,
    u16* __restrict__ wsa_b, u16* __restrict__ wsao_b, u16* __restrict__ wval_b,
    u16* __restrict__ wcao_b, u16* __restrict__ wff1_b, u16* __restrict__ wff2_b,
    u16* __restrict__ wofaw, float* __restrict__ obc, u16* __restrict__ src_b)
{
  long u = (long)blockIdx.x * 256 + threadIdx.x;
  if (u < 147456) { ((short8*)wsa_b)[u]  = cvt8(sa_in_w  + u * 8); return; } u -= 147456;
  if (u < 49152)  { ((short8*)wsao_b)[u] = cvt8(sa_out_w + u * 8); return; } u -= 49152;
  if (u < 49152)  { ((short8*)wval_b)[u] = cvt8(val_w    + u * 8); return; } u -= 49152;
  if (u < 49152)  { ((short8*)wcao_b)[u] = cvt8(cout_w   + u * 8); return; } u -= 49152;
  if (u < 196608) { ((short8*)wff1_b)[u] = cvt8(ff1w     + u * 8); return; } u -= 196608;
  if (u < 196608) { ((short8*)wff2_b)[u] = cvt8(ff2w     + u * 8); return; } u -= 196608;
  if (u < 12288)  { long e = u * 8; int l = (int)(e >> 14); long rem = e & 16383;
                    ((short8*)wofaw)[(l * 24576 + rem) >> 3] = cvt8(off_w + e); return; } u -= 12288;
  if (u < 6144)   { long e = u * 8; int l = (int)(e >> 13); long rem = e & 8191;
                    ((short8*)wofaw)[(l * 24576 + 16384 + rem) >> 3] = cvt8(aw_w + e); return; } u -= 6144;
  if (u < 3840000){ ((short8*)src_b)[u]  = cvt8(src + u * 8); return; } u -= 3840000;
  if (u < 72) {
    long e0 = u * 8;
#pragma unroll
    for (int j = 0; j < 8; j++) {
      long e = e0 + j;
      if (e < 384) { int l = (int)(e >> 6); obc[l * 96 + (e & 63)] = off_b[e]; }
      else { long e2 = e - 384; int l = (int)(e2 >> 5); obc[l * 96 + 64 + (e2 & 31)] = aw_b[e2]; }
    }
  }
}

// ---------------------------------------------------------------------------
// gemm_w_k<MT>: MT(M) x 256(N) block; 4 waves side-by-side (wave = 64 cols).
// A chunk (MT x 256) staged in LDS via global_load_lds(16B); W streamed (L2).
// z-batched via wZ/bZ/cZ strides. Optional RELU / bf16-out / fused V^T /
// fused residual+LayerNorm epilogue. Grid must exactly cover M (grid.x*MT)
// and N (grid.y*256); K % 256 == 0.
// ---------------------------------------------------------------------------
template<int MT, bool RELU, bool OUTBF, bool VT, bool LN>
__global__ __launch_bounds__(256) void gemm_w_k(
    const u16* __restrict__ A, int lda,
    const u16* __restrict__ W, long wZ,
    const float* __restrict__ bias, int bZ,
    void* __restrict__ Cv, int ldo, long cZ,
    int K,
    u16* __restrict__ vt,
    const float* __restrict__ res,
    const float* __restrict__ lnw, const float* __restrict__ lnb,
    const float* __restrict__ qpos,
    float* __restrict__ out_f, u16* __restrict__ out_b16,
    u16* __restrict__ qk_b16, float* __restrict__ hsp)
{
  __shared__ u16 As[32 * MT * 8];
  __shared__ float r1s[4][64], r2s[4][64], mArr[64], iArr[64];
  const int wave = threadIdx.x >> 6, lane = threadIdx.x & 63;
  const int bm = blockIdx.x * MT;
  const int bn = blockIdx.y * 256 + wave * 64;
  const int lr = lane & 15, lq = lane >> 4;
  constexpr int SH = (MT == 64) ? 6 : 5;
  const u16* Wz = W + (long)blockIdx.z * wZ;
  const float* bz = bias + (long)blockIdx.z * bZ;
  f32x4 acc[MT / 16][4] = {};
  const int nchunks = K >> 8;
  for (int ch = 0; ch < nchunks; ch++) {
#pragma unroll
    for (int it = 0; it < MT / 8; it++) {
      int ub = wave * (MT * 8) + it * 64;
      int u = ub + lane;
      int row = u & (MT - 1), kgrp = u >> SH;
      const u16* ga = A + (long)(bm + row) * lda + ch * 256 + kgrp * 8;
      __builtin_amdgcn_global_load_lds(
          (const __attribute__((address_space(1))) void*)ga,
          (__attribute__((address_space(3))) void*)(As + ub * 8), 16, 0, 0);
    }
    __syncthreads();
#pragma unroll
    for (int s = 0; s < 8; s++) {
      short8 af[MT / 16], bf[4];
#pragma unroll
      for (int i = 0; i < MT / 16; i++)
        af[i] = *(const short8*)(As + ((s * 4 + lq) * MT + i * 16 + lr) * 8);
#pragma unroll
      for (int j = 0; j < 4; j++) {
        int cc = bn + j * 16 + lr;
        bf[j] = *(const short8*)(Wz + (long)cc * K + ch * 256 + s * 32 + lq * 8);
      }
#pragma unroll
      for (int i = 0; i < MT / 16; i++)
#pragma unroll
        for (int j = 0; j < 4; j++)
          acc[i][j] = __builtin_amdgcn_mfma_f32_16x16x32_bf16(af[i], bf[j], acc[i][j], 0, 0, 0);
    }
    __syncthreads();
  }

  float bv[4];
#pragma unroll
  for (int j = 0; j < 4; j++) bv[j] = bz[bn + j * 16 + lr];

  if (!LN) {
    char* Cz = (char*)Cv;
#pragma unroll
    for (int j = 0; j < 4; j++) {
      int cc = bn + j * 16 + lr;
#pragma unroll
      for (int i = 0; i < MT / 16; i++) {
#pragma unroll
        for (int r = 0; r < 4; r++) {
          int rr = bm + i * 16 + lq * 4 + r;
          float v = acc[i][j][r] + bv[j];
          if (RELU) v = fmaxf(v, 0.f);
          long idx = (long)blockIdx.z * cZ + (long)rr * ldo + cc;
          if (OUTBF) ((u16*)Cz)[idx] = f2b(v);
          else       ((float*)Cz)[idx] = v;
          if (VT) {
            int b_ = rr >> 10, q_ = rr & 1023, h_ = cc >> 5, dh_ = cc & 31;
            vt[(long)((((b_ << 3) + h_) << 5) + dh_) * 1024 + q_] = f2b(v);
          }
        }
      }
    }
  } else {
    float s1[MT / 16][4] = {}, s2[MT / 16][4] = {};
#pragma unroll
    for (int i = 0; i < MT / 16; i++) {
#pragma unroll
      for (int r = 0; r < 4; r++) {
        int rowg = bm + i * 16 + lq * 4 + r;
#pragma unroll
        for (int j = 0; j < 4; j++) {
          int cc = bn + j * 16 + lr;
          float x = acc[i][j][r] + bv[j] + res[(long)rowg * 256 + cc];
          s1[i][r] += x; s2[i][r] += x * x;
        }
      }
    }
#pragma unroll
    for (int i = 0; i < MT / 16; i++)
#pragma unroll
      for (int r = 0; r < 4; r++) {
#pragma unroll
        for (int m = 1; m <= 8; m <<= 1) {
          s1[i][r] += __shfl_xor(s1[i][r], m);
          s2[i][r] += __shfl_xor(s2[i][r], m);
        }
      }
    if (lr == 0) {
#pragma unroll
      for (int i = 0; i < MT / 16; i++)
#pragma unroll
        for (int r = 0; r < 4; r++) {
          int rl = i * 16 + lq * 4 + r;
          r1s[wave][rl] = s1[i][r];
          r2s[wave][rl] = s2[i][r];
        }
    }
    __syncthreads();
    if (threadIdx.x < MT) {
      int t = threadIdx.x;
      float a = r1s[0][t] + r1s[1][t] + r1s[2][t] + r1s[3][t];
      float b = r2s[0][t] + r2s[1][t] + r2s[2][t] + r2s[3][t];
      float m = a * (1.f / 256.f);
      float var = b * (1.f / 256.f) - m * m;
      mArr[t] = m;
      iArr[t] = rsqrtf(var + 1e-5f);
    }
    __syncthreads();
#pragma unroll
    for (int i = 0; i < MT / 16; i++) {
#pragma unroll
      for (int r = 0; r < 4; r++) {
        int rl = i * 16 + lq * 4 + r;
        int rowg = bm + rl;
        float m = mArr[rl], inv = iArr[rl];
#pragma unroll
        for (int j = 0; j < 4; j++) {
          int cc = bn + j * 16 + lr;
          long idx = (long)rowg * 256 + cc;
          float x = acc[i][j][r] + bv[j] + res[idx];
          float y = (x - m) * inv * lnw[cc] + lnb[cc];
          out_f[idx] = y;
          if (out_b16) out_b16[idx] = f2b(y);
          if (qk_b16)  qk_b16[idx]  = f2b(y + qpos[idx]);
          if (hsp)     hsp[idx]     = y;
        }
      }
    }
  }
}

// ---------------------------------------------------------------------------
// qkv_k: merged Q/K/V projection. grid (64, 3): y=0 -> Q cols of qkbuf,
// y=1 -> K cols, y=2 -> V (writes vt only). MT=64 core identical to gemm_w_k.
// ---------------------------------------------------------------------------
__global__ __launch_bounds__(256) void qkv_k(
    const u16* __restrict__ qk_b, const u16* __restrict__ out_b,
    const u16* __restrict__ wsa, const float* __restrict__ bsa,
    u16* __restrict__ qkbuf, u16* __restrict__ vt)
{
  __shared__ u16 As[32 * 64 * 8];
  const int sel = blockIdx.y;
  const u16* A = (sel == 2) ? out_b : qk_b;
  const u16* W = wsa + (long)sel * 256 * 256;
  const int wave = threadIdx.x >> 6, lane = threadIdx.x & 63;
  const int bm = blockIdx.x * 64;
  const int bn = wave * 64;
  const int lr = lane & 15, lq = lane >> 4;
  f32x4 acc[4][4] = {};
#pragma unroll
  for (int it = 0; it < 8; it++) {
    int ub = wave * 512 + it * 64;
    int u = ub + lane;
    int row = u & 63, kgrp = u >> 6;
    const u16* ga = A + (long)(bm + row) * 256 + kgrp * 8;
    __builtin_amdgcn_global_load_lds(
        (const __attribute__((address_space(1))) void*)ga,
        (__attribute__((address_space(3))) void*)(As + ub * 8), 16, 0, 0);
  }
  __syncthreads();
#pragma unroll
  for (int s = 0; s < 8; s++) {
    short8 af[4], bf[4];
#pragma unroll
    for (int i = 0; i < 4; i++)
      af[i] = *(const short8*)(As + ((s * 4 + lq) * 64 + i * 16 + lr) * 8);
#pragma unroll
    for (int j = 0; j < 4; j++) {
      int cc = bn + j * 16 + lr;
      bf[j] = *(const short8*)(W + (long)cc * 256 + s * 32 + lq * 8);
    }
#pragma unroll
    for (int i = 0; i < 4; i++)
#pragma unroll
      for (int j = 0; j < 4; j++)
        acc[i][j] = __builtin_amdgcn_mfma_f32_16x16x32_bf16(af[i], bf[j], acc[i][j], 0, 0, 0);
  }
  float bv[4];
#pragma unroll
  for (int j = 0; j < 4; j++) bv[j] = bsa[sel * 256 + bn + j * 16 + lr];
#pragma unroll
  for (int j = 0; j < 4; j++) {
    int cc = bn + j * 16 + lr;
#pragma unroll
    for (int i = 0; i < 4; i++) {
#pragma unroll
      for (int r = 0; r < 4; r++) {
        int rr = bm + i * 16 + lq * 4 + r;
        float v = acc[i][j][r] + bv[j];
        if (sel < 2) {
          qkbuf[(long)rr * 512 + sel * 256 + cc] = f2b(v);
        } else {
          int b_ = rr >> 10, q_ = rr & 1023, h_ = cc >> 5, dh_ = cc & 31;
          vt[(long)((((b_ << 3) + h_) << 5) + dh_) * 1024 + q_] = f2b(v);
        }
      }
    }
  }
}

// ---------------------------------------------------------------------------
// Flash self-attention (round-6 proven): block per (b,h,q-tile 128).
// ---------------------------------------------------------------------------
__global__ __launch_bounds__(256) void flash_k(
    const u16* __restrict__ qkbuf, const u16* __restrict__ vt,
    u16* __restrict__ obuf)
{
  const float SC = 0.17677669529663687f;
  __shared__ u16 Plds[4][32][136];
  const int bh = blockIdx.x >> 3;
  const int b = bh >> 3, h = bh & 7;
  const int qt = blockIdx.x & 7;
  const int wave = threadIdx.x >> 6, lane = threadIdx.x & 63;
  const int lr = lane & 15, lq = lane >> 4;
  const int qbase = qt * 128 + wave * 32;

  short8 qf[2];
#pragma unroll
  for (int i = 0; i < 2; i++)
    qf[i] = *(const short8*)(qkbuf + (long)(b * 1024 + qbase + i * 16 + lr) * 512 + h * 32 + lq * 8);

  const u16* Kb = qkbuf + (long)b * 1024 * 512 + 256 + h * 32;
  const u16* Vb = vt + (long)bh * 32 * 1024;

  f32x4 acc_o[2][2] = {};
  float m_run[2][4], l_run[2][4];
#pragma unroll
  for (int i = 0; i < 2; i++)
#pragma unroll
    for (int r = 0; r < 4; r++){ m_run[i][r] = -3e38f; l_run[i][r] = 0.f; }

  for (int kt = 0; kt < 8; kt++) {
    f32x4 s[2][8] = {};
#pragma unroll
    for (int j = 0; j < 8; j++) {
      short8 kf = *(const short8*)(Kb + (long)(kt * 128 + j * 16 + lr) * 512 + lq * 8);
#pragma unroll
      for (int i = 0; i < 2; i++)
        s[i][j] = __builtin_amdgcn_mfma_f32_16x16x32_bf16(qf[i], kf, s[i][j], 0, 0, 0);
    }
#pragma unroll
    for (int i = 0; i < 2; i++) {
#pragma unroll
      for (int r = 0; r < 4; r++) {
        float mx = s[i][0][r];
#pragma unroll
        for (int j = 1; j < 8; j++) mx = fmaxf(mx, s[i][j][r]);
#pragma unroll
        for (int m = 1; m <= 8; m <<= 1) mx = fmaxf(mx, __shfl_xor(mx, m));
        float m_new = fmaxf(m_run[i][r], mx);
        float alpha = __expf((m_run[i][r] - m_new) * SC);
        float sum = 0.f;
        int row = i * 16 + lq * 4 + r;
#pragma unroll
        for (int j = 0; j < 8; j++) {
          float p = __expf((s[i][j][r] - m_new) * SC);
          sum += p;
          Plds[wave][row][j * 16 + lr] = f2b(p);
        }
#pragma unroll
        for (int m = 1; m <= 8; m <<= 1) sum += __shfl_xor(sum, m);
        l_run[i][r] = l_run[i][r] * alpha + sum;
        m_run[i][r] = m_new;
#pragma unroll
        for (int d = 0; d < 2; d++) acc_o[i][d][r] *= alpha;
      }
    }
#pragma unroll
    for (int kc = 0; kc < 4; kc++) {
      short8 pf[2];
#pragma unroll
      for (int i = 0; i < 2; i++)
        pf[i] = *(const short8*)&Plds[wave][i * 16 + lr][kc * 32 + lq * 8];
#pragma unroll
      for (int d = 0; d < 2; d++) {
        short8 vf = *(const short8*)(Vb + (long)(d * 16 + lr) * 1024 + kt * 128 + kc * 32 + lq * 8);
#pragma unroll
        for (int i = 0; i < 2; i++)
          acc_o[i][d] = __builtin_amdgcn_mfma_f32_16x16x32_bf16(pf[i], vf, acc_o[i][d], 0, 0, 0);
      }
    }
  }
#pragma unroll
  for (int i = 0; i < 2; i++) {
#pragma unroll
    for (int r = 0; r < 4; r++) {
      float inv = 1.f / l_run[i][r];
      int q = qbase + i * 16 + lq * 4 + r;
#pragma unroll
      for (int d = 0; d < 2; d++)
        obuf[(long)(b * 1024 + q) * 256 + h * 32 + d * 16 + lr] = f2b(acc_o[i][d][r] * inv);
    }
  }
}

// ---------------------------------------------------------------------------
// gemm64_k (bf16-only): 64x64 block, direct loads. Used for offaw (N=96).
// ---------------------------------------------------------------------------
__global__ __launch_bounds__(256) void gemm64_k(
    const u16* __restrict__ A, int lda,
    const u16* __restrict__ W, int ldw,
    const float* __restrict__ bias,
    float* __restrict__ C, int ldo,
    int M, int N, int K)
{
  const int wave = threadIdx.x >> 6, lane = threadIdx.x & 63;
  const int wm = wave >> 1, wn = wave & 1;
  const int bm = blockIdx.x * 64 + wm * 32;
  const int bn = blockIdx.y * 64 + wn * 32;
  const int lr = lane & 15, lq = lane >> 4;
  const int koff = lq * 8;
  f32x4 acc[2][2] = {};
  const short8 Z8 = {0,0,0,0,0,0,0,0};
  for (int k0 = 0; k0 < K; k0 += 32) {
    short8 af[2], bf[2];
#pragma unroll
    for (int i = 0; i < 2; i++) {
      int r = bm + i * 16 + lr;
      af[i] = (r < M) ? *(const short8*)(A + (long)r * lda + k0 + koff) : Z8;
    }
#pragma unroll
    for (int j = 0; j < 2; j++) {
      int c = bn + j * 16 + lr;
      bf[j] = (c < N) ? *(const short8*)(W + (long)c * ldw + k0 + koff) : Z8;
    }
#pragma unroll
    for (int i = 0; i < 2; i++)
#pragma unroll
      for (int j = 0; j < 2; j++)
        acc[i][j] = __builtin_amdgcn_mfma_f32_16x16x32_bf16(af[i], bf[j], acc[i][j], 0, 0, 0);
  }
#pragma unroll
  for (int j = 0; j < 2; j++) {
    int cc = bn + j * 16 + lr;
    if (cc >= N) continue;
    float bv = bias[cc];
#pragma unroll
    for (int i = 0; i < 2; i++) {
#pragma unroll
      for (int r = 0; r < 4; r++) {
        int rr = bm + i * 16 + lq * 4 + r;
        if (rr >= M) continue;
        C[(long)rr * ldo + cc] = acc[i][j][r] + bv;
      }
    }
  }
}

__global__ __launch_bounds__(256) void init_prep_k(const float* __restrict__ q, const float* __restrict__ qpos,
                                                   float* __restrict__ out_f, u16* __restrict__ out_b,
                                                   u16* __restrict__ qk_b){
  long i = (long)blockIdx.x * 256 + threadIdx.x;
  float o = q[i];
  out_f[i] = o;
  out_b[i] = f2b(o);
  qk_b[i]  = f2b(o + qpos[i]);
}

__global__ __launch_bounds__(256) void msda_k(
    const float* __restrict__ refp,
    const float* __restrict__ off, int ldoff,
    const float* __restrict__ aw, int ldaw,
    const u16* __restrict__ v,
    u16* __restrict__ o,
    long vstride)
{
  int tid = blockIdx.x * 256 + threadIdx.x;
  int dh = tid & 31;
  int h  = (tid >> 5) & 7;
  int bq = tid >> 8;
  int b  = bq >> 10;
  float rx = refp[bq * 2 + 0];
  float ry = refp[bq * 2 + 1];
  const float* offp = off + (long)bq * ldoff + h * 8;
  const float* awp  = aw  + (long)bq * ldaw + h * 4;
  float a0 = awp[0], a1 = awp[1], a2 = awp[2], a3 = awp[3];
  float am = fmaxf(fmaxf(a0, a1), fmaxf(a2, a3));
  float e[4];
  e[0] = __expf(a0 - am); e[1] = __expf(a1 - am); e[2] = __expf(a2 - am); e[3] = __expf(a3 - am);
  float einv = 1.f / (e[0] + e[1] + e[2] + e[3]);
  const u16* vb = v + b * vstride + h * 32 + dh;
  float accv = 0.f;
#pragma unroll
  for (int pp = 0; pp < 4; pp++){
    float x = rx * 150.f + offp[pp * 2 + 0] - 0.5f;
    float y = ry * 200.f + offp[pp * 2 + 1] - 0.5f;
    float x0 = floorf(x), y0 = floorf(y);
    float s = 0.f;
#pragma unroll
    for (int c = 0; c < 4; c++){
      int dx = c & 1, dy = c >> 1;
      float xi = x0 + dx, yi = y0 + dy;
      float wt = (1.f - fabsf(x - xi)) * (1.f - fabsf(y - yi));
      if (xi >= 0.f && xi < 150.f && yi >= 0.f && yi < 200.f && wt > 0.f) {
        int xc = (int)xi, yc = (int)yi;
        s += wt * b2f(vb[((long)yc * 150 + xc) * 256]);
      }
    }
    accv += e[pp] * einv * s;
  }
  o[(long)bq * 256 + h * 32 + dh] = f2b(accv);
}

__global__ __launch_bounds__(256) void refs_k(const float* __restrict__ r, float* __restrict__ dst){
  int i = blockIdx.x * 256 + threadIdx.x;
  dst[i] = r[i & 8191];
}

// ---------------------------------------------------------------------------
extern "C" void kernel_launch(void* const* d_in, const int* in_sizes, int n_in,
                              void* d_out, int out_size, void* d_ws, size_t ws_size,
                              hipStream_t stream)
{
  (void)in_sizes; (void)n_in; (void)out_size;
  const float* query = (const float*)d_in[0];
  const float* qpos  = (const float*)d_in[1];
  const float* refp  = (const float*)d_in[2];
  const float* src   = (const float*)d_in[3];
  const float* sa_in_w  = (const float*)d_in[6];
  const float* sa_in_b  = (const float*)d_in[7];
  const float* sa_out_w = (const float*)d_in[8];
  const float* sa_out_b = (const float*)d_in[9];
  const float* off_w = (const float*)d_in[10];
  const float* off_b = (const float*)d_in[11];
  const float* aw_w  = (const float*)d_in[12];
  const float* aw_b  = (const float*)d_in[13];
  const float* val_w = (const float*)d_in[14];
  const float* val_b = (const float*)d_in[15];
  const float* cout_w = (const float*)d_in[16];
  const float* cout_b = (const float*)d_in[17];
  const float* n1w = (const float*)d_in[18]; const float* n1b = (const float*)d_in[19];
  const float* n2w = (const float*)d_in[20]; const float* n2b = (const float*)d_in[21];
  const float* n3w = (const float*)d_in[22]; const float* n3b = (const float*)d_in[23];
  const float* ff1w = (const float*)d_in[24]; const float* ff1b = (const float*)d_in[25];
  const float* ff2w = (const float*)d_in[26]; const float* ff2b = (const float*)d_in[27];

  float* hs = (float*)d_out;
  float* refs_out = hs + (long)6 * 4096 * 256;

  char* p = (char*)d_ws;
  auto alloc = [&](size_t bytes){ char* r = p; p += (bytes + 255) & ~(size_t)255; return r; };
  float* out_f = (float*)alloc(4194304);
  u16*   qk_b  = (u16*)  alloc(2097152);
  u16*   out_b = (u16*)  alloc(2097152);
  u16* wsa_b  = (u16*)alloc(2359296);
  u16* wsao_b = (u16*)alloc(786432);
  u16* wofaw  = (u16*)alloc(294912);
  u16* wval_b = (u16*)alloc(786432);
  u16* wcao_b = (u16*)alloc(786432);
  u16* wff1_b = (u16*)alloc(3145728);
  u16* wff2_b = (u16*)alloc(3145728);
  float* obc  = (float*)alloc(2304);
  u16* src_b  = (u16*)alloc(61440000);
  u16* qkbuf  = (u16*)alloc(4194304);
  u16* vt     = (u16*)alloc(2097152);
  u16* obuf   = (u16*)alloc(2097152);
  float* oawo = (float*)alloc(1572864);
  u16* mo     = (u16*)alloc(2097152);
  u16* ffh    = (u16*)alloc(8388608);
  size_t used = (size_t)(p - (char*)d_ws);
  const bool big = (ws_size >= used + 368640000ull);   // room for 6-layer vsrc
  u16* vsrc = (u16*)alloc(big ? 368640000ull : 61440000ull);

  init_prep_k<<<4096, 256, 0, stream>>>(query, qpos, out_f, out_b, qk_b);
  cvtall_k<<<17761, 256, 0, stream>>>(sa_in_w, sa_out_w, val_w, cout_w, ff1w, ff2w,
                                      off_w, aw_w, off_b, aw_b, src,
                                      wsa_b, wsao_b, wval_b, wcao_b, wff1_b, wff2_b,
                                      wofaw, obc, src_b);
  if (big) {
    // all 6 layers' value projections in one launch (independent of layer loop)
    gemm_w_k<64,false,true,false,false><<<dim3(1875,1,6),256,0,stream>>>(
        src_b, 256, wval_b, 65536, val_b, 256, vsrc, 256, 30720000, 256,
        nullptr, nullptr,nullptr,nullptr,nullptr,nullptr,nullptr,nullptr,nullptr);
  }

  for (int l = 0; l < 6; l++){
    const u16* wsa = wsa_b + (long)l * 768 * 256;
    // ---- self attention (flash) ----
    qkv_k<<<dim3(64,3,1),256,0,stream>>>(qk_b, out_b, wsa, sa_in_b + l * 768, qkbuf, vt);
    flash_k<<<256,256,0,stream>>>(qkbuf, vt, obuf);
    gemm_w_k<32,false,false,false,true><<<dim3(128,1,1),256,0,stream>>>(   // out-proj + norm2
        obuf, 256, wsao_b + (long)l*65536, 0, sa_out_b + l*256, 0, nullptr, 0, 0, 256,
        nullptr, out_f, n2w + l*256, n2b + l*256, qpos, out_f, nullptr, qk_b, nullptr);
    // ---- deformable cross attention ----
    gemm64_k<<<dim3(64,2,1),256,0,stream>>>(qk_b, 256, wofaw + (long)l*24576, 256,
        obc + l*96, oawo, 96, 4096, 96, 256);
    if (!big) {
      gemm_w_k<64,false,true,false,false><<<dim3(1875,1,1),256,0,stream>>>(
          src_b, 256, wval_b + (long)l*65536, 0, val_b + l*256, 0, vsrc, 256, 0, 256,
          nullptr, nullptr,nullptr,nullptr,nullptr,nullptr,nullptr,nullptr,nullptr);
    }
    const u16* vsl = big ? (vsrc + (long)l*30720000) : vsrc;
    msda_k<<<4096,256,0,stream>>>(refp, oawo, 96, oawo + 64, 96, vsl, mo, 7680000);
    gemm_w_k<32,false,false,false,true><<<dim3(128,1,1),256,0,stream>>>(   // ca-out + norm1
        mo, 256, wcao_b + (long)l*65536, 0, cout_b + l*256, 0, nullptr, 0, 0, 256,
        nullptr, out_f, n1w + l*256, n1b + l*256, nullptr, out_f, out_b, nullptr, nullptr);
    // ---- ffn ----
    gemm_w_k<64,true,true,false,false><<<dim3(64,4,1),256,0,stream>>>(     // ff1 + relu
        out_b, 256, wff1_b + (long)l*262144, 0, ff1b + l*1024, 0, ffh, 1024, 0, 256,
        nullptr, nullptr,nullptr,nullptr,nullptr,nullptr,nullptr,nullptr,nullptr);
    gemm_w_k<32,false,false,false,true><<<dim3(128,1,1),256,0,stream>>>(   // ff2 + norm3
        ffh, 1024, wff2_b + (long)l*262144, 0, ff2b + l*256, 0, nullptr, 0, 0, 1024,
        nullptr, out_f, n3w + l*256, n3b + l*256, qpos, out_f, out_b, qk_b,
        hs + (long)l*1048576);
  }
  refs_k<<<192,256,0,stream>>>(refp, refs_out);
}